// Round 4
// baseline (115.905 us; speedup 1.0000x reference)
//
#include <hip/hip_runtime.h>

// y = convT3d(x, weight.sum(oc), stride=2, pad=2, k=5) + sum(bias); out = 6^3 stride-6 max.
// Tap algebra (verified R1-R3, absmax 0.0): y[o] = sum_id x[id]*w[k], k = o+2-2*id in [0,4].
// Only y[0:30, 0:60, 0:60] feeds pooling.
// Stage1 tile: 6od x 30oh x 30ow per (n, dc, hq, wq, chunk). 225 compute threads (mw15 x lmh15),
// each owns acc[3 md][2 dt][2 ht][2 wt] = 24 outputs. Double-buffered LDS staging (T14):
// issue next-phase global loads -> compute current -> ds_write other buffer -> ONE barrier.

#define DIN 16
#define HIN 32
#define WIN 32
#define CHSTR (DIN*HIN*WIN)      // 16384
#define NSTRIDE (32*CHSTR)
#define Y_N 108000               // 30*60*60
#define Y_TOT (16*Y_N)
#define XSTR 24                  // LDS row stride (floats); 20 cols used

// ---- tap macro: acc[m][dt][ht][wt] over w taps; x0,x1,x2 = cols cb..cb+2 ----
#define TAP(m,dt,kd,ht,kh) { const float* wr = wc + ((kd)*5+(kh))*5; \
  acc[m][dt][ht][0] += x0*wr[4]; acc[m][dt][ht][0] += x1*wr[2]; acc[m][dt][ht][0] += x2*wr[0]; \
  acc[m][dt][ht][1] += x1*wr[3]; acc[m][dt][ht][1] += x2*wr[1]; }

#define DT0(HT,KH) TAP(0,0,4,HT,KH)
#define DT1(HT,KH) TAP(1,0,4,HT,KH) TAP(0,0,2,HT,KH) TAP(0,1,3,HT,KH)
#define DT2(HT,KH) TAP(2,0,4,HT,KH) TAP(1,0,2,HT,KH) TAP(1,1,3,HT,KH) TAP(0,0,0,HT,KH) TAP(0,1,1,HT,KH)
#define DT3(HT,KH) TAP(2,0,2,HT,KH) TAP(2,1,3,HT,KH) TAP(1,0,0,HT,KH) TAP(1,1,1,HT,KH)
#define DT4(HT,KH) TAP(2,0,0,HT,KH) TAP(2,1,1,HT,KH)

#define ROWB(AD,DB,TAPS) { const float* xr = xb + (AD)*(17*XSTR) + (DB)*XSTR; \
  float x0 = xr[0], x1 = xr[1], x2 = xr[2]; TAPS }

#define ADROWS(AD,DTX) \
  ROWB(AD,0, DTX(0,4)) \
  ROWB(AD,1, DTX(0,2) DTX(1,3)) \
  ROWB(AD,2, DTX(0,0) DTX(1,1))

template<int NCHUNK>
__global__ __launch_bounds__(256, 4) void conv_stage1(const float* __restrict__ x,
                                                      const float* __restrict__ ws,
                                                      float* part, int woff) {
  constexpr int ICPB = 32 / NCHUNK;    // channels per block
  constexpr int NPHS = ICPB / 2;       // 2-channel phases
  __shared__ __align__(16) float xs[2][170 * XSTR];   // double buffer

  int blk = blockIdx.x;
  int s0  = blk % 320;
  int chunk = blk / 320;
  int wq = s0 & 1;
  int hq = (s0 >> 1) & 1;
  int dc = (s0 >> 2) % 5;
  int n  = s0 / 20;
  int t  = threadIdx.x;

  int mw  = t % 15;
  int lmh = t / 15;          // valid for t<225

  int id_base = 3 * dc - 1;
  int ih_base = 15 * hq - 1;
  int iwb     = wq ? 12 : -4;          // col c <-> iw = iwb + c
  int cb      = mw + (wq ? 2 : 3);     // read base col

  const float* xn  = x + (size_t)n * NSTRIDE + (size_t)(chunk * ICPB) * CHSTR;
  const float* wsw = ws + woff + (size_t)(chunk * ICPB) * 128;

  // ---- precompute 7 staging slots per thread (addresses, masks, LDS offsets)
  const float* sga[7];
  int  slds[7];
  bool sv[7], sw[7];
#pragma unroll
  for (int j = 0; j < 7; ++j) {
    int s   = t + 256 * j;
    int c2  = s % 10;
    int row = s / 10;          // 0..169
    int bh  = row % 17;
    int q   = row / 17;
    int ad  = q % 5, lic = q / 5;
    int id = id_base + ad;
    int ih = ih_base + bh;
    int iw = iwb + 2 * c2;
    sw[j] = (s < 1700);
    sv[j] = sw[j] && ((id | ih | iw) >= 0);   // uppers provably in range
    sga[j] = xn + (size_t)lic * CHSTR + (id * HIN + ih) * WIN + iw;
    slds[j] = row * XSTR + 2 * c2;
  }

  float2 stg[7];
#define LOADP(PHS) { _Pragma("unroll") \
  for (int j = 0; j < 7; ++j) { \
    stg[j] = make_float2(0.f, 0.f); \
    if (sv[j]) stg[j] = *(const float2*)(sga[j] + (size_t)(PHS) * 2 * CHSTR); } }

#define WRITEP(BUF) { float* bb = xs[BUF]; _Pragma("unroll") \
  for (int j = 0; j < 7; ++j) if (sw[j]) *(float2*)&bb[slds[j]] = stg[j]; }

  float acc[3][2][2][2] = {{{{0.f}}}};

  LOADP(0);
  WRITEP(0);
  __syncthreads();

  for (int phs = 0; phs < NPHS; ++phs) {
    if (phs + 1 < NPHS) LOADP(phs + 1);       // issue early; vmcnt waited at WRITEP

    if (t < 225) {
      const float* xbase = &xs[phs & 1][lmh * XSTR + cb];
      {
        const float* wc = wsw + (size_t)(phs * 2) * 128;
        const float* xb = xbase;
        ADROWS(0,DT0) ADROWS(1,DT1) ADROWS(2,DT2) ADROWS(3,DT3) ADROWS(4,DT4)
      }
      {
        const float* wc = wsw + (size_t)(phs * 2 + 1) * 128;
        const float* xb = xbase + 85 * XSTR;
        ADROWS(0,DT0) ADROWS(1,DT1) ADROWS(2,DT2) ADROWS(3,DT3) ADROWS(4,DT4)
      }
    }
    if (phs + 1 < NPHS) {
      WRITEP((phs + 1) & 1);                  // other buffer: no pre-barrier needed
      __syncthreads();                        // one barrier per phase
    }
  }

  if (t < 225) {
    float* pb = part + (size_t)chunk * Y_TOT + (size_t)n * Y_N;
#pragma unroll
    for (int m = 0; m < 3; ++m)
#pragma unroll
      for (int dt = 0; dt < 2; ++dt)
#pragma unroll
        for (int ht = 0; ht < 2; ++ht) {
          int od_g = 6 * dc + 2 * m + dt;
          int oh_g = 30 * hq + 2 * lmh + ht;
          int ow_g = 30 * wq + 2 * mw;
          *(float2*)&pb[(od_g * 60 + oh_g) * 60 + ow_g] =
              make_float2(acc[m][dt][ht][0], acc[m][dt][ht][1]);
        }
  }
}

// ---------------- stage 2: chunk-sum + 6^3 max + bias ------------------
// 800 blocks = (n, dc, hc); 240 active threads = (wc 10) x (sub 24); 9 elems each.
template<int NCHUNK>
__global__ __launch_bounds__(256) void pool_stage2(const float* __restrict__ part,
                                                   const float* __restrict__ ws,
                                                   float* __restrict__ out, int woff) {
  __shared__ float red[240];
  int blk = blockIdx.x;
  int hc = blk % 10;
  int dc = (blk / 10) % 5;
  int n  = blk / 50;
  int t = threadIdx.x;
  const float* pb = part + (size_t)n * Y_N;
  float m = -3.4e38f;
  if (t < 240) {
    int wc = t / 24, sub = t % 24;
#pragma unroll
    for (int k = 0; k < 9; ++k) {
      int e = sub + 24 * k;          // 0..215
      int od = e / 36, r = e % 36;
      int oh = r / 6, ow0 = r % 6;
      size_t idx = (size_t)((6 * dc + od) * 60 + 6 * hc + oh) * 60 + 6 * wc + ow0;
      float v = pb[idx];
#pragma unroll
      for (int c = 1; c < NCHUNK; ++c) v += pb[(size_t)c * Y_TOT + idx];
      m = fmaxf(m, v);
    }
    red[t] = m;
  }
  __syncthreads();
  if (t < 10) {
    float mm = -3.4e38f;
#pragma unroll
    for (int s = 0; s < 24; ++s) mm = fmaxf(mm, red[t * 24 + s]);
    out[((n * 5 + dc) * 10 + hc) * 10 + t] = mm + ws[woff + 4096];
  }
}

// ---------------- prep: weight oc-sum + bias sum -----------------------
__global__ __launch_bounds__(128) void prep2(const float* __restrict__ w,
                                             const float* __restrict__ bias,
                                             float* __restrict__ ws, int woff) {
  int i = blockIdx.x, t = threadIdx.x;
  if (t < 125) {
    const float* wp = w + (size_t)i * 64 * 125 + t;
    float v = 0.f;
#pragma unroll
    for (int o = 0; o < 64; ++o) v += wp[o * 125];   // 64 loads in flight
    ws[woff + i * 128 + t] = v;
  }
  if (i == 0 && t == 126) {
    float b = 0.f;
    for (int o = 0; o < 64; ++o) b += bias[o];
    ws[woff + 4096] = b;
  }
}

// ================= fallback (round-1 kernels, need only ~64 KB ws) ======
__global__ __launch_bounds__(256) void prep_kernel(const float* __restrict__ w,
                                                   const float* __restrict__ bias,
                                                   float* __restrict__ ws) {
  int i = blockIdx.x;
  int t = threadIdx.x;
  for (int s = t; s < 512; s += 256) {
    int kw = s & 7, kh = (s >> 3) & 7, kd = s >> 6;
    float v = 0.f;
    if (kd < 5 && kh < 5 && kw < 5) {
      const float* wp = w + (size_t)i * 64 * 125 + kd * 25 + kh * 5 + kw;
#pragma unroll 8
      for (int o = 0; o < 64; ++o) v += wp[o * 125];
    }
    ws[i * 512 + s] = v;
  }
  if (i == 0 && t == 0) {
    float b = 0.f;
    for (int o = 0; o < 64; ++o) b += bias[o];
    ws[16384] = b;
  }
}

__global__ __launch_bounds__(192) void conv_pool_kernel(const float* __restrict__ x,
                                                        const float* __restrict__ ws,
                                                        float* __restrict__ out) {
  __shared__ __align__(16) float xs[4080];
  __shared__ __align__(16) float wl[3200];
  __shared__ float red[360];
  int b = blockIdx.x;
  int wc2 = b % 5, hq = (b / 5) % 2, dc = (b / 10) % 5, n = b / 50;
  int t = threadIdx.x;
  int td = t / 30, ohl = t % 30;
  int a0 = (td + 1) >> 1, b0 = (ohl + 1) >> 1;
  const float* xn = x + (size_t)n * NSTRIDE;
  int id_base = 3 * dc - 1, ih_base = 15 * hq - 1, iw_base = 6 * wc2 - 1;
  float acc0=0,acc1=0,acc2=0,acc3=0,acc4=0,acc5=0,acc6=0,acc7=0,acc8=0,acc9=0,acc10=0,acc11=0;
  for (int p = 0; p < 8; ++p) {
    for (int s = t; s < 2720; s += 192) {
      int c = s & 7; int r = s >> 3; int bh = r % 17; int r2 = r / 17;
      int ad = r2 % 5; int ic = r2 / 5;
      int id = id_base + ad, ih = ih_base + bh, iw = iw_base + c;
      float v = 0.f;
      if ((id | ih | iw) >= 0)
        v = xn[(size_t)(p * 4 + ic) * CHSTR + id * (HIN * WIN) + ih * WIN + iw];
      xs[(ic * 5 + ad) * 204 + bh * 12 + c] = v;
    }
    for (int s = t; s < 2048; s += 192) {
      int kw = s & 7, kh = (s >> 3) & 7, kd = (s >> 6) & 7, ic = s >> 9;
      wl[ic * 800 + kd * 100 + kh * 12 + kw] = ws[(p * 4 + ic) * 512 + (s & 511)];
    }
    __syncthreads();
    if (t < 180) {
      for (int ic = 0; ic < 4; ++ic) {
        const float* xc = &xs[ic * 1020];
        const float* wcc = &wl[ic * 800];
#pragma unroll
        for (int jd = 0; jd < 3; ++jd) {
          int ad = a0 + jd;
          int kd = (td + 4 - 2 * ad) & 7;
          if (ad > 4) ad = 4;
#pragma unroll
          for (int jh = 0; jh < 3; ++jh) {
            int bh = b0 + jh;
            int kh = (ohl + 4 - 2 * bh) & 7;
            if (bh > 16) bh = 16;
            const float* xr = xc + ad * 204 + bh * 12;
            const float* wr = wcc + kd * 100 + kh * 12;
            float4 xlo = *(const float4*)(xr);
            float4 xhi = *(const float4*)(xr + 4);
            float4 wv = *(const float4*)(wr);
            float w4 = wr[4];
            float x0=xlo.x,x1=xlo.y,x2=xlo.z,x3=xlo.w,x4=xhi.x,x5=xhi.y,x6=xhi.z,x7=xhi.w;
            float w0=wv.x,w1=wv.y,w2=wv.z,w3=wv.w;
            acc0+=x0*w4; acc0+=x1*w2; acc0+=x2*w0; acc1+=x1*w3; acc1+=x2*w1;
            acc2+=x1*w4; acc2+=x2*w2; acc2+=x3*w0; acc3+=x2*w3; acc3+=x3*w1;
            acc4+=x2*w4; acc4+=x3*w2; acc4+=x4*w0; acc5+=x3*w3; acc5+=x4*w1;
            acc6+=x3*w4; acc6+=x4*w2; acc6+=x5*w0; acc7+=x4*w3; acc7+=x5*w1;
            acc8+=x4*w4; acc8+=x5*w2; acc8+=x6*w0; acc9+=x5*w3; acc9+=x6*w1;
            acc10+=x5*w4; acc10+=x6*w2; acc10+=x7*w0; acc11+=x6*w3; acc11+=x7*w1;
          }
        }
      }
    }
    __syncthreads();
  }
  if (t < 180) {
    float g0 = fmaxf(fmaxf(fmaxf(acc0,acc1),fmaxf(acc2,acc3)),fmaxf(acc4,acc5));
    float g1 = fmaxf(fmaxf(fmaxf(acc6,acc7),fmaxf(acc8,acc9)),fmaxf(acc10,acc11));
    red[t * 2] = g0; red[t * 2 + 1] = g1;
  }
  __syncthreads();
  if (t < 10) {
    int hs = t >> 1, wsub = t & 1;
    float m = -3.4e38f;
    for (int tdd = 0; tdd < 6; ++tdd)
      for (int j = 0; j < 6; ++j) m = fmaxf(m, red[(tdd * 30 + hs * 6 + j) * 2 + wsub]);
    m += ws[16384];
    out[((n * 5 + dc) * 10 + (5 * hq + hs)) * 10 + (2 * wc2 + wsub)] = m;
  }
}

// ---------------- launch ----------------------------------------------
extern "C" void kernel_launch(void* const* d_in, const int* in_sizes, int n_in,
                              void* d_out, int out_size, void* d_ws, size_t ws_size,
                              hipStream_t stream) {
  const float* x    = (const float*)d_in[0];
  const float* w    = (const float*)d_in[1];
  const float* bias = (const float*)d_in[2];
  float* outp = (float*)d_out;
  float* ws   = (float*)d_ws;

  const size_t need4 = ((size_t)4 * Y_TOT + 4097) * 4;
  const size_t need2 = ((size_t)2 * Y_TOT + 4097) * 4;
  const size_t need1 = ((size_t)1 * Y_TOT + 4097) * 4;

  if (ws_size >= need4) {
    int woff = 4 * Y_TOT;
    prep2<<<32, 128, 0, stream>>>(w, bias, ws, woff);
    conv_stage1<4><<<320 * 4, 256, 0, stream>>>(x, ws, ws, woff);
    pool_stage2<4><<<800, 256, 0, stream>>>(ws, ws, outp, woff);
  } else if (ws_size >= need2) {
    int woff = 2 * Y_TOT;
    prep2<<<32, 128, 0, stream>>>(w, bias, ws, woff);
    conv_stage1<2><<<320 * 2, 256, 0, stream>>>(x, ws, ws, woff);
    pool_stage2<2><<<800, 256, 0, stream>>>(ws, ws, outp, woff);
  } else if (ws_size >= need1) {
    int woff = 1 * Y_TOT;
    prep2<<<32, 128, 0, stream>>>(w, bias, ws, woff);
    conv_stage1<1><<<320 * 1, 256, 0, stream>>>(x, ws, ws, woff);
    pool_stage2<1><<<800, 256, 0, stream>>>(ws, ws, outp, woff);
  } else {
    prep_kernel<<<32, 256, 0, stream>>>(w, bias, ws);
    conv_pool_kernel<<<800, 192, 0, stream>>>(x, ws, outp);
  }
}

// Round 5
// 100.614 us; speedup vs baseline: 1.1520x; 1.1520x over previous
//
#include <hip/hip_runtime.h>

// y = convT3d(x, weight.sum(oc), stride=2, pad=2, k=5) + sum(bias); out = 6^3 stride-6 max.
// Tap algebra (verified R1-R4, absmax 0.0): y[o] = sum_id x[id]*w[k], k = o+2-2*id in [0,4].
// Only y[0:30, 0:60, 0:60] feeds pooling.
// Stage1 tile: 6od x 30oh x 30ow per (n, dc, hq, wq, chunk). 225 compute threads (mw15 x lmh15),
// each owns acc[3 m][2 dt][2 ht][2 wt] = 24 outputs.
// R5: per channel, thread loads its 45-float x working set into regs (one lgkmcnt wait),
// then kd-major weight batching (25 uniform s_loads per kd) -> 375 reg-only FMAs/channel.

#define DIN 16
#define HIN 32
#define WIN 32
#define CHSTR (DIN*HIN*WIN)      // 16384
#define NSTRIDE (32*CHSTR)
#define Y_N 108000               // 30*60*60
#define Y_TOT (16*Y_N)
#define XSTR 24                  // LDS row stride (floats); 20 cols used

template<int NCHUNK>
__global__ __launch_bounds__(256, 4) void conv_stage1(const float* __restrict__ x,
                                                      const float* __restrict__ ws,
                                                      float* part, int woff) {
  constexpr int ICPB = 32 / NCHUNK;    // channels per block
  constexpr int NPHS = ICPB / 2;       // 2-channel phases
  __shared__ __align__(16) float xs[170 * XSTR];   // 2ch x 5 planes x 17 rows, 16.3 KB

  int blk = blockIdx.x;
  int s0  = blk % 320;
  int chunk = blk / 320;
  int wq = s0 & 1;
  int hq = (s0 >> 1) & 1;
  int dc = (s0 >> 2) % 5;
  int n  = s0 / 20;
  int t  = threadIdx.x;

  int mw  = t % 15;
  int lmh = t / 15;          // valid for t<225

  int id_base = 3 * dc - 1;
  int ih_base = 15 * hq - 1;
  int iwb     = wq ? 12 : -4;          // col c <-> iw = iwb + c
  int cb      = mw + (wq ? 2 : 3);     // read base col

  const float* xn  = x + (size_t)n * NSTRIDE + (size_t)(chunk * ICPB) * CHSTR;
  const float* wsw = ws + woff + (size_t)(chunk * ICPB) * 128;

  float acc[3][2][2][2] = {{{{0.f}}}};

  for (int phs = 0; phs < NPHS; ++phs) {
    // ---- stage 2 channels: 170 rows x 10 float2 (cols 0..19; halo cols -> 0)
    for (int s = t; s < 1700; s += 256) {
      int c2  = s % 10;
      int row = s / 10;          // 0..169
      int bh  = row % 17;
      int q   = row / 17;
      int ad  = q % 5, lic = q / 5;
      int id = id_base + ad;
      int ih = ih_base + bh;
      int iw = iwb + 2 * c2;
      float2 v = make_float2(0.f, 0.f);
      if ((id | ih | iw) >= 0)   // uppers provably in range
        v = *(const float2*)&xn[(size_t)(phs * 2 + lic) * CHSTR + (id * HIN + ih) * WIN + iw];
      *(float2*)&xs[row * XSTR + 2 * c2] = v;
    }
    __syncthreads();

    if (t < 225) {
#pragma unroll
      for (int lic = 0; lic < 2; ++lic) {
        const float* wc = wsw + (size_t)(phs * 2 + lic) * 128;
        const float* xc = &xs[(lic * 85 + lmh) * XSTR + cb];
        // ---- load thread's x working set: 15 rows x 3 cols
        float xv[5][3][3];
#pragma unroll
        for (int a = 0; a < 5; ++a)
#pragma unroll
          for (int b = 0; b < 3; ++b) {
            const float* xr = xc + (a * 17 + b) * XSTR;
            xv[a][b][0] = xr[0]; xv[a][b][1] = xr[1]; xv[a][b][2] = xr[2];
          }
        // ---- kd-major: 25 uniform weights per kd, then 75 reg-only FMAs
#pragma unroll
        for (int kd = 0; kd < 5; ++kd) {
          constexpr int DT[5]   = {0, 1, 0, 1, 0};
          constexpr int AOFF[5] = {2, 2, 1, 1, 0};
          const int dt = DT[kd], aoff = AOFF[kd];
          float wv[25];
#pragma unroll
          for (int j = 0; j < 25; ++j) wv[j] = wc[kd * 25 + j];
#pragma unroll
          for (int kh = 0; kh < 5; ++kh) {
            constexpr int HT[5]   = {0, 1, 0, 1, 0};
            constexpr int BOFF[5] = {2, 2, 1, 1, 0};
            const int ht = HT[kh], boff = BOFF[kh];
#pragma unroll
            for (int m = 0; m < 3; ++m) {
              const float x0 = xv[m + aoff][boff][0];
              const float x1 = xv[m + aoff][boff][1];
              const float x2 = xv[m + aoff][boff][2];
              acc[m][dt][ht][0] += x0 * wv[kh * 5 + 4];
              acc[m][dt][ht][0] += x1 * wv[kh * 5 + 2];
              acc[m][dt][ht][0] += x2 * wv[kh * 5 + 0];
              acc[m][dt][ht][1] += x1 * wv[kh * 5 + 3];
              acc[m][dt][ht][1] += x2 * wv[kh * 5 + 1];
            }
          }
        }
      }
    }
    __syncthreads();
  }

  if (t < 225) {
    float* pb = part + (size_t)chunk * Y_TOT + (size_t)n * Y_N;
#pragma unroll
    for (int m = 0; m < 3; ++m)
#pragma unroll
      for (int dt = 0; dt < 2; ++dt)
#pragma unroll
        for (int ht = 0; ht < 2; ++ht) {
          int od_g = 6 * dc + 2 * m + dt;
          int oh_g = 30 * hq + 2 * lmh + ht;
          int ow_g = 30 * wq + 2 * mw;
          *(float2*)&pb[(od_g * 60 + oh_g) * 60 + ow_g] =
              make_float2(acc[m][dt][ht][0], acc[m][dt][ht][1]);
        }
  }
}

// ---------------- stage 2: chunk-sum (coalesced, LDS) + 6^3 max + bias --
// 800 blocks = (n, dc, hc); sums 6od x 6oh x 60ow tile across chunks, then 10 outputs.
template<int NCHUNK>
__global__ __launch_bounds__(256) void pool_stage2(const float* __restrict__ part,
                                                   const float* __restrict__ ws,
                                                   float* __restrict__ out, int woff) {
  __shared__ __align__(16) float buf[2160];
  __shared__ float red[240];
  int blk = blockIdx.x;
  int hc = blk % 10;
  int dc = (blk / 10) % 5;
  int n  = blk / 50;
  int t = threadIdx.x;
  const float* pb = part + (size_t)n * Y_N;
  // 36 rows of 60 floats = 540 float4, coalesced
  for (int s = t; s < 540; s += 256) {
    int row = s / 15;          // od*6+oh, 0..35
    int c4  = s % 15;
    int od = row / 6, oh = row % 6;
    size_t idx = (size_t)((6 * dc + od) * 60 + (6 * hc + oh)) * 60 + 4 * c4;
    float4 v = *(const float4*)&pb[idx];
#pragma unroll
    for (int c = 1; c < NCHUNK; ++c) {
      float4 u = *(const float4*)&pb[(size_t)c * Y_TOT + idx];
      v.x += u.x; v.y += u.y; v.z += u.z; v.w += u.w;
    }
    *(float4*)&buf[row * 60 + 4 * c4] = v;
  }
  __syncthreads();
  if (t < 240) {
    int wc = t / 24, sub = t % 24;
    float m = -3.4e38f;
#pragma unroll
    for (int k = 0; k < 9; ++k) {
      int e = sub + 24 * k;    // 0..215
      int od = e / 36, r = e % 36;
      int oh = r / 6, ow0 = r % 6;
      m = fmaxf(m, buf[(od * 6 + oh) * 60 + 6 * wc + ow0]);
    }
    red[t] = m;
  }
  __syncthreads();
  if (t < 10) {
    float mm = -3.4e38f;
#pragma unroll
    for (int s2 = 0; s2 < 24; ++s2) mm = fmaxf(mm, red[t * 24 + s2]);
    out[((n * 5 + dc) * 10 + hc) * 10 + t] = mm + ws[woff + 4096];
  }
}

// ---------------- prep: weight oc-sum + bias sum -----------------------
__global__ __launch_bounds__(128) void prep2(const float* __restrict__ w,
                                             const float* __restrict__ bias,
                                             float* __restrict__ ws, int woff) {
  int i = blockIdx.x, t = threadIdx.x;
  if (t < 125) {
    const float* wp = w + (size_t)i * 64 * 125 + t;
    float v = 0.f;
#pragma unroll
    for (int o = 0; o < 64; ++o) v += wp[o * 125];   // 64 loads in flight
    ws[woff + i * 128 + t] = v;
  }
  if (i == 0 && t == 126) {
    float b = 0.f;
    for (int o = 0; o < 64; ++o) b += bias[o];
    ws[woff + 4096] = b;
  }
}

// ================= fallback (round-1 kernels, need only ~64 KB ws) ======
__global__ __launch_bounds__(256) void prep_kernel(const float* __restrict__ w,
                                                   const float* __restrict__ bias,
                                                   float* __restrict__ ws) {
  int i = blockIdx.x;
  int t = threadIdx.x;
  for (int s = t; s < 512; s += 256) {
    int kw = s & 7, kh = (s >> 3) & 7, kd = s >> 6;
    float v = 0.f;
    if (kd < 5 && kh < 5 && kw < 5) {
      const float* wp = w + (size_t)i * 64 * 125 + kd * 25 + kh * 5 + kw;
#pragma unroll 8
      for (int o = 0; o < 64; ++o) v += wp[o * 125];
    }
    ws[i * 512 + s] = v;
  }
  if (i == 0 && t == 0) {
    float b = 0.f;
    for (int o = 0; o < 64; ++o) b += bias[o];
    ws[16384] = b;
  }
}

__global__ __launch_bounds__(192) void conv_pool_kernel(const float* __restrict__ x,
                                                        const float* __restrict__ ws,
                                                        float* __restrict__ out) {
  __shared__ __align__(16) float xs[4080];
  __shared__ __align__(16) float wl[3200];
  __shared__ float red[360];
  int b = blockIdx.x;
  int wc2 = b % 5, hq = (b / 5) % 2, dc = (b / 10) % 5, n = b / 50;
  int t = threadIdx.x;
  int td = t / 30, ohl = t % 30;
  int a0 = (td + 1) >> 1, b0 = (ohl + 1) >> 1;
  const float* xn = x + (size_t)n * NSTRIDE;
  int id_base = 3 * dc - 1, ih_base = 15 * hq - 1, iw_base = 6 * wc2 - 1;
  float acc0=0,acc1=0,acc2=0,acc3=0,acc4=0,acc5=0,acc6=0,acc7=0,acc8=0,acc9=0,acc10=0,acc11=0;
  for (int p = 0; p < 8; ++p) {
    for (int s = t; s < 2720; s += 192) {
      int c = s & 7; int r = s >> 3; int bh = r % 17; int r2 = r / 17;
      int ad = r2 % 5; int ic = r2 / 5;
      int id = id_base + ad, ih = ih_base + bh, iw = iw_base + c;
      float v = 0.f;
      if ((id | ih | iw) >= 0)
        v = xn[(size_t)(p * 4 + ic) * CHSTR + id * (HIN * WIN) + ih * WIN + iw];
      xs[(ic * 5 + ad) * 204 + bh * 12 + c] = v;
    }
    for (int s = t; s < 2048; s += 192) {
      int kw = s & 7, kh = (s >> 3) & 7, kd = (s >> 6) & 7, ic = s >> 9;
      wl[ic * 800 + kd * 100 + kh * 12 + kw] = ws[(p * 4 + ic) * 512 + (s & 511)];
    }
    __syncthreads();
    if (t < 180) {
      for (int ic = 0; ic < 4; ++ic) {
        const float* xc = &xs[ic * 1020];
        const float* wcc = &wl[ic * 800];
#pragma unroll
        for (int jd = 0; jd < 3; ++jd) {
          int ad = a0 + jd;
          int kd = (td + 4 - 2 * ad) & 7;
          if (ad > 4) ad = 4;
#pragma unroll
          for (int jh = 0; jh < 3; ++jh) {
            int bh = b0 + jh;
            int kh = (ohl + 4 - 2 * bh) & 7;
            if (bh > 16) bh = 16;
            const float* xr = xc + ad * 204 + bh * 12;
            const float* wr = wcc + kd * 100 + kh * 12;
            float4 xlo = *(const float4*)(xr);
            float4 xhi = *(const float4*)(xr + 4);
            float4 wv = *(const float4*)(wr);
            float w4 = wr[4];
            float x0=xlo.x,x1=xlo.y,x2=xlo.z,x3=xlo.w,x4=xhi.x,x5=xhi.y,x6=xhi.z,x7=xhi.w;
            float w0=wv.x,w1=wv.y,w2=wv.z,w3=wv.w;
            acc0+=x0*w4; acc0+=x1*w2; acc0+=x2*w0; acc1+=x1*w3; acc1+=x2*w1;
            acc2+=x1*w4; acc2+=x2*w2; acc2+=x3*w0; acc3+=x2*w3; acc3+=x3*w1;
            acc4+=x2*w4; acc4+=x3*w2; acc4+=x4*w0; acc5+=x3*w3; acc5+=x4*w1;
            acc6+=x3*w4; acc6+=x4*w2; acc6+=x5*w0; acc7+=x4*w3; acc7+=x5*w1;
            acc8+=x4*w4; acc8+=x5*w2; acc8+=x6*w0; acc9+=x5*w3; acc9+=x6*w1;
            acc10+=x5*w4; acc10+=x6*w2; acc10+=x7*w0; acc11+=x6*w3; acc11+=x7*w1;
          }
        }
      }
    }
    __syncthreads();
  }
  if (t < 180) {
    float g0 = fmaxf(fmaxf(fmaxf(acc0,acc1),fmaxf(acc2,acc3)),fmaxf(acc4,acc5));
    float g1 = fmaxf(fmaxf(fmaxf(acc6,acc7),fmaxf(acc8,acc9)),fmaxf(acc10,acc11));
    red[t * 2] = g0; red[t * 2 + 1] = g1;
  }
  __syncthreads();
  if (t < 10) {
    int hs = t >> 1, wsub = t & 1;
    float m = -3.4e38f;
    for (int tdd = 0; tdd < 6; ++tdd)
      for (int j = 0; j < 6; ++j) m = fmaxf(m, red[(tdd * 30 + hs * 6 + j) * 2 + wsub]);
    m += ws[16384];
    out[((n * 5 + dc) * 10 + (5 * hq + hs)) * 10 + (2 * wc2 + wsub)] = m;
  }
}

// ---------------- launch ----------------------------------------------
extern "C" void kernel_launch(void* const* d_in, const int* in_sizes, int n_in,
                              void* d_out, int out_size, void* d_ws, size_t ws_size,
                              hipStream_t stream) {
  const float* x    = (const float*)d_in[0];
  const float* w    = (const float*)d_in[1];
  const float* bias = (const float*)d_in[2];
  float* outp = (float*)d_out;
  float* ws   = (float*)d_ws;

  const size_t need8 = ((size_t)8 * Y_TOT + 4097) * 4;
  const size_t need4 = ((size_t)4 * Y_TOT + 4097) * 4;
  const size_t need2 = ((size_t)2 * Y_TOT + 4097) * 4;
  const size_t need1 = ((size_t)1 * Y_TOT + 4097) * 4;

  if (ws_size >= need8) {
    int woff = 8 * Y_TOT;
    prep2<<<32, 128, 0, stream>>>(w, bias, ws, woff);
    conv_stage1<8><<<320 * 8, 256, 0, stream>>>(x, ws, ws, woff);
    pool_stage2<8><<<800, 256, 0, stream>>>(ws, ws, outp, woff);
  } else if (ws_size >= need4) {
    int woff = 4 * Y_TOT;
    prep2<<<32, 128, 0, stream>>>(w, bias, ws, woff);
    conv_stage1<4><<<320 * 4, 256, 0, stream>>>(x, ws, ws, woff);
    pool_stage2<4><<<800, 256, 0, stream>>>(ws, ws, outp, woff);
  } else if (ws_size >= need2) {
    int woff = 2 * Y_TOT;
    prep2<<<32, 128, 0, stream>>>(w, bias, ws, woff);
    conv_stage1<2><<<320 * 2, 256, 0, stream>>>(x, ws, ws, woff);
    pool_stage2<2><<<800, 256, 0, stream>>>(ws, ws, outp, woff);
  } else if (ws_size >= need1) {
    int woff = 1 * Y_TOT;
    prep2<<<32, 128, 0, stream>>>(w, bias, ws, woff);
    conv_stage1<1><<<320 * 1, 256, 0, stream>>>(x, ws, ws, woff);
    pool_stage2<1><<<800, 256, 0, stream>>>(ws, ws, outp, woff);
  } else {
    prep_kernel<<<32, 256, 0, stream>>>(w, bias, ws);
    conv_pool_kernel<<<800, 192, 0, stream>>>(x, ws, outp);
  }
}

// Round 6
// 56.532 us; speedup vs baseline: 2.0503x; 1.7798x over previous
//
#include <hip/hip_runtime.h>

// y = convT3d(x, weight.sum(oc), stride=2, pad=2, k=5) + sum(bias); out = 6^3 stride-6 max.
// MFMA formulation: y[2m+t] = sum_{ic,a,b,c} x[ic, m+1-(a,b,c)] * w[ic, t+2(a,b,c)]
//   D[16 cells x 16 parities(8 used)] += A[cells x 32ic] * B[32ic x parities], 27 (a,b,c) chunks.
// xT: bf16 [n][dpad 18][hpad 34][wpad 34][ic 32], halos zeroed -> A-frag = coalesced 1KB global load.
// Btab: bf16 MFMA B-fragment layout [27 abc][64 lane][8], zero-padded taps -> exact.
// conv_mfma: 800 blocks (n,OD,OH) x 9 waves (md,mh); fused 6^3 pool from LDS ytile.

typedef short v8s __attribute__((ext_vector_type(8)));
typedef float v4f __attribute__((ext_vector_type(4)));
typedef unsigned short ushort_t;

#define DIN 16
#define HIN 32
#define WIN 32
#define CHSTR (DIN*HIN*WIN)      // 16384
#define NSTRIDE (32*CHSTR)
#define Y_N 108000
#define Y_TOT (16*Y_N)
#define XSTR 24

#define XT_US 10653696u          // 16*18*34*34*32 ushorts
#define XTN   665856u            // per-n: 18*34*34*32
#define PLANE_US 36992u          // 34*34*32
#define ROW_US 1088u             // 34*32
#define BT_BYTE_OFF 21307392u    // XT_US*2
#define WSF_BYTE_OFF 21335040u   // +27*64*8*2
#define NEED_MFMA (21335040u + 4097u*4u)

static __device__ __forceinline__ ushort_t f2bf(float f) {
  unsigned u = __builtin_bit_cast(unsigned, f);
  unsigned r = (u + 0x7FFFu + ((u >> 16) & 1u)) >> 16;
  return (ushort_t)r;
}

// ---------------- prep: weight oc-sum + bias sum (fp32) ----------------
__global__ __launch_bounds__(128) void prep_w(const float* __restrict__ w,
                                              const float* __restrict__ bias,
                                              float* __restrict__ wsf) {
  int i = blockIdx.x, t = threadIdx.x;
  if (t < 125) {
    const float* wp = w + (size_t)i * 64 * 125 + t;
    float v = 0.f;
#pragma unroll
    for (int o = 0; o < 64; ++o) v += wp[o * 125];
    wsf[i * 128 + t] = v;
  }
  if (i == 0 && t == 126) {
    float b = 0.f;
    for (int o = 0; o < 64; ++o) b += bias[o];
    wsf[4096] = b;
  }
}

// ---------------- prep: B fragment table (bf16) ------------------------
__global__ __launch_bounds__(64) void prep_b(const float* __restrict__ wsf,
                                             ushort_t* __restrict__ Btab) {
  int abc = blockIdx.x;               // a*9 + b*3 + c
  int a = abc / 9, b = (abc / 3) % 3, c = abc % 3;
  int l = threadIdx.x;
  int tt = l & 15, g = l >> 4;
  ushort_t o[8];
#pragma unroll
  for (int j = 0; j < 8; ++j) {
    int ic = 8 * g + j;
    float v = 0.f;
    if (tt < 8) {
      int td = tt & 1, th = (tt >> 1) & 1, tw = tt >> 2;
      int kd = td + 2 * a, kh = th + 2 * b, kw = tw + 2 * c;
      if (kd < 5 && kh < 5 && kw < 5) v = wsf[ic * 128 + kd * 25 + kh * 5 + kw];
    }
    o[j] = f2bf(v);
  }
  uint4 pk;
  pk.x = (unsigned)o[0] | ((unsigned)o[1] << 16);
  pk.y = (unsigned)o[2] | ((unsigned)o[3] << 16);
  pk.z = (unsigned)o[4] | ((unsigned)o[5] << 16);
  pk.w = (unsigned)o[6] | ((unsigned)o[7] << 16);
  *(uint4*)&Btab[(abc * 64 + l) * 8] = pk;
}

// ---------------- transpose x -> xT bf16 with halos --------------------
// grid: (n*18 + dpad)*4 + hq ; 256 threads
__global__ __launch_bounds__(256) void transpose_x(const float* __restrict__ x,
                                                   ushort_t* __restrict__ xT) {
  int blk = blockIdx.x;
  int hq = blk & 3;
  int dpad = (blk >> 2) % 18;
  int n = blk / 72;
  int t = threadIdx.x;
  int h0 = 8 * hq;
  int hcnt = (hq == 3) ? 10 : 8;
  ushort_t* plane = xT + (size_t)(n * 18 + dpad) * PLANE_US;
  int d = dpad - 1;

  if (d < 0 || d > 15) {     // zero plane slice
    for (int r = 0; r < hcnt; ++r) {
      char* row = (char*)(plane + (size_t)(h0 + r) * ROW_US);
      for (int s = t; s < 136; s += 256)
        *(uint4*)(row + s * 16) = make_uint4(0, 0, 0, 0);
    }
    return;
  }

  __shared__ float lb[2][32 * 33];
  const float* xb = x + ((size_t)n * 32 * 16 + d) * 1024;
  int ic = t >> 3, wq = t & 7;

  // prologue: load iter 0 (hpad = h0 -> h = h0-1)
  {
    int h = h0 - 1;
    if (h >= 0 && h <= 31) {
      float4 v = *(const float4*)&xb[(size_t)ic * 16384 + h * 32 + wq * 4];
      float* L = lb[0] + ic * 33 + wq * 4;
      L[0] = v.x; L[1] = v.y; L[2] = v.z; L[3] = v.w;
    }
  }
  int pp = 0;
  for (int i = 0; i < hcnt; ++i) {
    __syncthreads();
    if (i + 1 < hcnt) {
      int h = h0 + i;        // next iter's h = (h0+i+1)-1
      if (h >= 0 && h <= 31) {
        float4 v = *(const float4*)&xb[(size_t)ic * 16384 + h * 32 + wq * 4];
        float* L = lb[pp ^ 1] + ic * 33 + wq * 4;
        L[0] = v.x; L[1] = v.y; L[2] = v.z; L[3] = v.w;
      }
    }
    int h = h0 + i - 1;
    ushort_t* row = plane + (size_t)(h0 + i) * ROW_US;
    bool hv = (h >= 0 && h <= 31);
    for (int s = t; s < 272; s += 256) {
      int wslot = s >> 3, q = s & 7;
      ushort_t o0 = 0, o1 = 0, o2 = 0, o3 = 0;
      if (wslot >= 1 && wslot <= 32 && hv) {
        int w = wslot - 1;
        const float* L = lb[pp];
        o0 = f2bf(L[(4 * q + 0) * 33 + w]);
        o1 = f2bf(L[(4 * q + 1) * 33 + w]);
        o2 = f2bf(L[(4 * q + 2) * 33 + w]);
        o3 = f2bf(L[(4 * q + 3) * 33 + w]);
      }
      uint2 pk;
      pk.x = (unsigned)o0 | ((unsigned)o1 << 16);
      pk.y = (unsigned)o2 | ((unsigned)o3 << 16);
      *(uint2*)(row + wslot * 32 + q * 4) = pk;
    }
    pp ^= 1;
  }
}

// ---------------- fused MFMA conv + 6^3 pool ---------------------------
// 800 blocks = (n, OD, OH); 576 threads = 9 waves (mdl, mhl)
__global__ __launch_bounds__(576, 1) void conv_mfma(const ushort_t* __restrict__ xT,
                                                    const ushort_t* __restrict__ Btab,
                                                    const float* __restrict__ wsf,
                                                    float* __restrict__ out) {
  __shared__ ushort_t Bl[27 * 64 * 8];   // 27648 B
  __shared__ float ytile[6 * 6 * 64];    // 9216 B
  __shared__ float red[64];

  int blk = blockIdx.x;
  int OH = blk % 10, OD = (blk / 10) % 5, n = blk / 50;
  int t = threadIdx.x;

  for (int s = t; s < 1728; s += 576)
    *(uint4*)&Bl[s * 8] = *(const uint4*)&Btab[s * 8];

  int wv = t >> 6, l = t & 63;
  int mdl = wv / 3, mhl = wv % 3;
  int md = 3 * OD + mdl, mh = 3 * OH + mhl;
  int tt = l & 15, g = l >> 4;
  const ushort_t* xn = xT + (size_t)n * XTN;
  __syncthreads();

#pragma unroll
  for (int whalf = 0; whalf < 2; ++whalf) {
    int mw = 16 * whalf + tt;
    v4f acc = {0.f, 0.f, 0.f, 0.f};
#pragma unroll
    for (int a = 0; a < 3; ++a) {
      const ushort_t* pa = xn + (((size_t)(md + 2 - a) * 34 + (mh + 1)) * 34 + (mw + 1)) * 32 + g * 8;
#pragma unroll
      for (int b = 0; b < 3; ++b) {
#pragma unroll
        for (int c = 0; c < 3; ++c) {
          v8s av = *(const v8s*)(pa + ((1 - b) * 34 + (1 - c)) * 32);
          v8s bv = *(const v8s*)&Bl[(((a * 3 + b) * 3 + c) * 64 + l) * 8];
          acc = __builtin_amdgcn_mfma_f32_16x16x32_bf16(av, bv, acc, 0, 0, 0);
        }
      }
    }
    if (tt < 8) {
      int td = tt & 1, th = (tt >> 1) & 1, tw = tt >> 2;
      int odl = 2 * mdl + td, ohl = 2 * mhl + th;
#pragma unroll
      for (int i = 0; i < 4; ++i) {
        int mwD = 16 * whalf + 4 * g + i;
        ytile[(odl * 6 + ohl) * 64 + 2 * mwD + tw] = acc[i];
      }
    }
  }
  __syncthreads();

  if (t < 60) {
    int odl = t / 10, OW = t % 10;
    float m = -3.4e38f;
    for (int oh = 0; oh < 6; ++oh)
#pragma unroll
      for (int j = 0; j < 6; ++j)
        m = fmaxf(m, ytile[(odl * 6 + oh) * 64 + 6 * OW + j]);
    red[t] = m;
  }
  __syncthreads();
  if (t < 10) {
    float m = red[t];
#pragma unroll
    for (int odl = 1; odl < 6; ++odl) m = fmaxf(m, red[odl * 10 + t]);
    out[((n * 5 + OD) * 10 + OH) * 10 + t] = m + wsf[4096];
  }
}

// ================= fallback: R5 verified fp32 path =====================
template<int NCHUNK>
__global__ __launch_bounds__(256, 4) void conv_stage1(const float* __restrict__ x,
                                                      const float* __restrict__ ws,
                                                      float* part, int woff) {
  constexpr int ICPB = 32 / NCHUNK;
  constexpr int NPHS = ICPB / 2;
  __shared__ __align__(16) float xs[170 * XSTR];
  int blk = blockIdx.x;
  int s0 = blk % 320;
  int chunk = blk / 320;
  int wq = s0 & 1, hq = (s0 >> 1) & 1, dc = (s0 >> 2) % 5, n = s0 / 20;
  int t = threadIdx.x;
  int mw = t % 15, lmh = t / 15;
  int id_base = 3 * dc - 1, ih_base = 15 * hq - 1;
  int iwb = wq ? 12 : -4;
  int cb = mw + (wq ? 2 : 3);
  const float* xn = x + (size_t)n * NSTRIDE + (size_t)(chunk * ICPB) * CHSTR;
  const float* wsw = ws + woff + (size_t)(chunk * ICPB) * 128;
  float acc[3][2][2][2] = {{{{0.f}}}};
  for (int phs = 0; phs < NPHS; ++phs) {
    for (int s = t; s < 1700; s += 256) {
      int c2 = s % 10, row = s / 10;
      int bh = row % 17, q = row / 17;
      int ad = q % 5, lic = q / 5;
      int id = id_base + ad, ih = ih_base + bh, iw = iwb + 2 * c2;
      float2 v = make_float2(0.f, 0.f);
      if ((id | ih | iw) >= 0)
        v = *(const float2*)&xn[(size_t)(phs * 2 + lic) * CHSTR + (id * HIN + ih) * WIN + iw];
      *(float2*)&xs[row * XSTR + 2 * c2] = v;
    }
    __syncthreads();
    if (t < 225) {
#pragma unroll
      for (int lic = 0; lic < 2; ++lic) {
        const float* wc = wsw + (size_t)(phs * 2 + lic) * 128;
        const float* xc = &xs[(lic * 85 + lmh) * XSTR + cb];
        float xv[5][3][3];
#pragma unroll
        for (int a = 0; a < 5; ++a)
#pragma unroll
          for (int b = 0; b < 3; ++b) {
            const float* xr = xc + (a * 17 + b) * XSTR;
            xv[a][b][0] = xr[0]; xv[a][b][1] = xr[1]; xv[a][b][2] = xr[2];
          }
#pragma unroll
        for (int kd = 0; kd < 5; ++kd) {
          constexpr int DT[5] = {0, 1, 0, 1, 0};
          constexpr int AOFF[5] = {2, 2, 1, 1, 0};
          const int dt = DT[kd], aoff = AOFF[kd];
          float wv[25];
#pragma unroll
          for (int j = 0; j < 25; ++j) wv[j] = wc[kd * 25 + j];
#pragma unroll
          for (int kh = 0; kh < 5; ++kh) {
            constexpr int HT[5] = {0, 1, 0, 1, 0};
            constexpr int BOFF[5] = {2, 2, 1, 1, 0};
            const int ht = HT[kh], boff = BOFF[kh];
#pragma unroll
            for (int m = 0; m < 3; ++m) {
              const float x0 = xv[m + aoff][boff][0];
              const float x1 = xv[m + aoff][boff][1];
              const float x2 = xv[m + aoff][boff][2];
              acc[m][dt][ht][0] += x0 * wv[kh * 5 + 4];
              acc[m][dt][ht][0] += x1 * wv[kh * 5 + 2];
              acc[m][dt][ht][0] += x2 * wv[kh * 5 + 0];
              acc[m][dt][ht][1] += x1 * wv[kh * 5 + 3];
              acc[m][dt][ht][1] += x2 * wv[kh * 5 + 1];
            }
          }
        }
      }
    }
    __syncthreads();
  }
  if (t < 225) {
    float* pb = part + (size_t)chunk * Y_TOT + (size_t)n * Y_N;
#pragma unroll
    for (int m = 0; m < 3; ++m)
#pragma unroll
      for (int dt = 0; dt < 2; ++dt)
#pragma unroll
        for (int ht = 0; ht < 2; ++ht) {
          int od_g = 6 * dc + 2 * m + dt;
          int oh_g = 30 * hq + 2 * lmh + ht;
          int ow_g = 30 * wq + 2 * mw;
          *(float2*)&pb[(od_g * 60 + oh_g) * 60 + ow_g] =
              make_float2(acc[m][dt][ht][0], acc[m][dt][ht][1]);
        }
  }
}

template<int NCHUNK>
__global__ __launch_bounds__(256) void pool_stage2(const float* __restrict__ part,
                                                   const float* __restrict__ ws,
                                                   float* __restrict__ out, int woff) {
  __shared__ __align__(16) float buf[2160];
  __shared__ float red[240];
  int blk = blockIdx.x;
  int hc = blk % 10, dc = (blk / 10) % 5, n = blk / 50;
  int t = threadIdx.x;
  const float* pb = part + (size_t)n * Y_N;
  for (int s = t; s < 540; s += 256) {
    int row = s / 15, c4 = s % 15;
    int od = row / 6, oh = row % 6;
    size_t idx = (size_t)((6 * dc + od) * 60 + (6 * hc + oh)) * 60 + 4 * c4;
    float4 v = *(const float4*)&pb[idx];
#pragma unroll
    for (int c = 1; c < NCHUNK; ++c) {
      float4 u = *(const float4*)&pb[(size_t)c * Y_TOT + idx];
      v.x += u.x; v.y += u.y; v.z += u.z; v.w += u.w;
    }
    *(float4*)&buf[row * 60 + 4 * c4] = v;
  }
  __syncthreads();
  if (t < 240) {
    int wc = t / 24, sub = t % 24;
    float m = -3.4e38f;
#pragma unroll
    for (int k = 0; k < 9; ++k) {
      int e = sub + 24 * k;
      int od = e / 36, r = e % 36;
      int oh = r / 6, ow0 = r % 6;
      m = fmaxf(m, buf[(od * 6 + oh) * 60 + 6 * wc + ow0]);
    }
    red[t] = m;
  }
  __syncthreads();
  if (t < 10) {
    float mm = -3.4e38f;
#pragma unroll
    for (int s2 = 0; s2 < 24; ++s2) mm = fmaxf(mm, red[t * 24 + s2]);
    out[((n * 5 + dc) * 10 + hc) * 10 + t] = mm + ws[woff + 4096];
  }
}

__global__ __launch_bounds__(128) void prep2(const float* __restrict__ w,
                                             const float* __restrict__ bias,
                                             float* __restrict__ ws, int woff) {
  int i = blockIdx.x, t = threadIdx.x;
  if (t < 125) {
    const float* wp = w + (size_t)i * 64 * 125 + t;
    float v = 0.f;
#pragma unroll
    for (int o = 0; o < 64; ++o) v += wp[o * 125];
    ws[woff + i * 128 + t] = v;
  }
  if (i == 0 && t == 126) {
    float b = 0.f;
    for (int o = 0; o < 64; ++o) b += bias[o];
    ws[woff + 4096] = b;
  }
}

// ---------------- launch ----------------------------------------------
extern "C" void kernel_launch(void* const* d_in, const int* in_sizes, int n_in,
                              void* d_out, int out_size, void* d_ws, size_t ws_size,
                              hipStream_t stream) {
  const float* x    = (const float*)d_in[0];
  const float* w    = (const float*)d_in[1];
  const float* bias = (const float*)d_in[2];
  float* outp = (float*)d_out;

  if (ws_size >= (size_t)NEED_MFMA) {
    ushort_t* xT = (ushort_t*)d_ws;
    ushort_t* Bt = (ushort_t*)((char*)d_ws + BT_BYTE_OFF);
    float* wsf   = (float*)((char*)d_ws + WSF_BYTE_OFF);
    prep_w<<<32, 128, 0, stream>>>(w, bias, wsf);
    prep_b<<<27, 64, 0, stream>>>(wsf, Bt);
    transpose_x<<<16 * 18 * 4, 256, 0, stream>>>(x, xT);
    conv_mfma<<<800, 576, 0, stream>>>(xT, Bt, wsf, outp);
    return;
  }

  float* ws = (float*)d_ws;
  const size_t need4 = ((size_t)4 * Y_TOT + 4097) * 4;
  const size_t need2 = ((size_t)2 * Y_TOT + 4097) * 4;
  const size_t need1 = ((size_t)1 * Y_TOT + 4097) * 4;
  if (ws_size >= need4) {
    int woff = 4 * Y_TOT;
    prep2<<<32, 128, 0, stream>>>(w, bias, ws, woff);
    conv_stage1<4><<<320 * 4, 256, 0, stream>>>(x, ws, ws, woff);
    pool_stage2<4><<<800, 256, 0, stream>>>(ws, ws, outp, woff);
  } else if (ws_size >= need2) {
    int woff = 2 * Y_TOT;
    prep2<<<32, 128, 0, stream>>>(w, bias, ws, woff);
    conv_stage1<2><<<320 * 2, 256, 0, stream>>>(x, ws, ws, woff);
    pool_stage2<2><<<800, 256, 0, stream>>>(ws, ws, outp, woff);
  } else if (ws_size >= need1) {
    int woff = 1 * Y_TOT;
    prep2<<<32, 128, 0, stream>>>(w, bias, ws, woff);
    conv_stage1<1><<<320 * 1, 256, 0, stream>>>(x, ws, ws, woff);
    pool_stage2<1><<<800, 256, 0, stream>>>(ws, ws, outp, woff);
  }
}

// Round 7
// 43.953 us; speedup vs baseline: 2.6370x; 1.2862x over previous
//
#include <hip/hip_runtime.h>

// y = convT3d(x, weight.sum(oc), stride=2, pad=2, k=5) + sum(bias); out = 6^3 stride-6 max.
// MFMA formulation (verified R6, absmax 0.25): y[2m+t] = sum_{ic,abc} x[ic, m+1-abc] * w[ic, t+2abc]
//   D[16 w-cells x 8 parities] += A[cells x 32ic] * B[32ic x parities], 27 (a,b,c) chunks.
// xT: bf16 [n][dpad 18][hpad 34][wpad 34][ic 32], halos zeroed.
// R7: conv stages A per dpad-plane in LDS (contiguous 10.9KB slab, double-buffered, T14 order),
//     B-frag register-reused across whalf -> 27 ds_read_b128 + 18 MFMA per active phase.

typedef short v8s __attribute__((ext_vector_type(8)));
typedef float v4f __attribute__((ext_vector_type(4)));
typedef unsigned short ushort_t;

#define DIN 16
#define HIN 32
#define WIN 32
#define CHSTR (DIN*HIN*WIN)      // 16384
#define NSTRIDE (32*CHSTR)
#define Y_N 108000
#define Y_TOT (16*Y_N)
#define XSTR 24

#define XT_US 10653696u          // 16*18*34*34*32 ushorts
#define XTN   665856u            // per-n: 18*34*34*32
#define PLANE_US 36992u          // 34*34*32
#define ROW_US 1088u             // 34*32
#define BT_BYTE_OFF 21307392u    // XT_US*2
#define WSF_BYTE_OFF 21335040u   // +27*64*8*2
#define NEED_MFMA (21335040u + 4097u*4u)

static __device__ __forceinline__ ushort_t f2bf(float f) {
  unsigned u = __builtin_bit_cast(unsigned, f);
  unsigned r = (u + 0x7FFFu + ((u >> 16) & 1u)) >> 16;
  return (ushort_t)r;
}

// ---------------- prep: weight oc-sum + bias sum (fp32) ----------------
__global__ __launch_bounds__(128) void prep_w(const float* __restrict__ w,
                                              const float* __restrict__ bias,
                                              float* __restrict__ wsf) {
  int i = blockIdx.x, t = threadIdx.x;
  if (t < 125) {
    const float* wp = w + (size_t)i * 64 * 125 + t;
    float v = 0.f;
#pragma unroll
    for (int o = 0; o < 64; ++o) v += wp[o * 125];
    wsf[i * 128 + t] = v;
  }
  if (i == 0 && t == 126) {
    float b = 0.f;
    for (int o = 0; o < 64; ++o) b += bias[o];
    wsf[4096] = b;
  }
}

// ---------------- prep: B fragment table (bf16) ------------------------
__global__ __launch_bounds__(64) void prep_b(const float* __restrict__ wsf,
                                             ushort_t* __restrict__ Btab) {
  int abc = blockIdx.x;               // a*9 + b*3 + c
  int a = abc / 9, b = (abc / 3) % 3, c = abc % 3;
  int l = threadIdx.x;
  int tt = l & 15, g = l >> 4;
  ushort_t o[8];
#pragma unroll
  for (int j = 0; j < 8; ++j) {
    int ic = 8 * g + j;
    float v = 0.f;
    if (tt < 8) {
      int td = tt & 1, th = (tt >> 1) & 1, tw = tt >> 2;
      int kd = td + 2 * a, kh = th + 2 * b, kw = tw + 2 * c;
      if (kd < 5 && kh < 5 && kw < 5) v = wsf[ic * 128 + kd * 25 + kh * 5 + kw];
    }
    o[j] = f2bf(v);
  }
  uint4 pk;
  pk.x = (unsigned)o[0] | ((unsigned)o[1] << 16);
  pk.y = (unsigned)o[2] | ((unsigned)o[3] << 16);
  pk.z = (unsigned)o[4] | ((unsigned)o[5] << 16);
  pk.w = (unsigned)o[6] | ((unsigned)o[7] << 16);
  *(uint4*)&Btab[(abc * 64 + l) * 8] = pk;
}

// ---------------- transpose x -> xT bf16 with halos --------------------
__global__ __launch_bounds__(256) void transpose_x(const float* __restrict__ x,
                                                   ushort_t* __restrict__ xT) {
  int blk = blockIdx.x;
  int hq = blk & 3;
  int dpad = (blk >> 2) % 18;
  int n = blk / 72;
  int t = threadIdx.x;
  int h0 = 8 * hq;
  int hcnt = (hq == 3) ? 10 : 8;
  ushort_t* plane = xT + (size_t)(n * 18 + dpad) * PLANE_US;
  int d = dpad - 1;

  if (d < 0 || d > 15) {
    for (int r = 0; r < hcnt; ++r) {
      char* row = (char*)(plane + (size_t)(h0 + r) * ROW_US);
      for (int s = t; s < 136; s += 256)
        *(uint4*)(row + s * 16) = make_uint4(0, 0, 0, 0);
    }
    return;
  }

  __shared__ float lb[2][32 * 33];
  const float* xb = x + ((size_t)n * 32 * 16 + d) * 1024;
  int ic = t >> 3, wq = t & 7;

  {
    int h = h0 - 1;
    if (h >= 0 && h <= 31) {
      float4 v = *(const float4*)&xb[(size_t)ic * 16384 + h * 32 + wq * 4];
      float* L = lb[0] + ic * 33 + wq * 4;
      L[0] = v.x; L[1] = v.y; L[2] = v.z; L[3] = v.w;
    }
  }
  int pp = 0;
  for (int i = 0; i < hcnt; ++i) {
    __syncthreads();
    if (i + 1 < hcnt) {
      int h = h0 + i;
      if (h >= 0 && h <= 31) {
        float4 v = *(const float4*)&xb[(size_t)ic * 16384 + h * 32 + wq * 4];
        float* L = lb[pp ^ 1] + ic * 33 + wq * 4;
        L[0] = v.x; L[1] = v.y; L[2] = v.z; L[3] = v.w;
      }
    }
    int h = h0 + i - 1;
    ushort_t* row = plane + (size_t)(h0 + i) * ROW_US;
    bool hv = (h >= 0 && h <= 31);
    for (int s = t; s < 272; s += 256) {
      int wslot = s >> 3, q = s & 7;
      ushort_t o0 = 0, o1 = 0, o2 = 0, o3 = 0;
      if (wslot >= 1 && wslot <= 32 && hv) {
        int w = wslot - 1;
        const float* L = lb[pp];
        o0 = f2bf(L[(4 * q + 0) * 33 + w]);
        o1 = f2bf(L[(4 * q + 1) * 33 + w]);
        o2 = f2bf(L[(4 * q + 2) * 33 + w]);
        o3 = f2bf(L[(4 * q + 3) * 33 + w]);
      }
      uint2 pk;
      pk.x = (unsigned)o0 | ((unsigned)o1 << 16);
      pk.y = (unsigned)o2 | ((unsigned)o3 << 16);
      *(uint2*)(row + wslot * 32 + q * 4) = pk;
    }
    pp ^= 1;
  }
}

// ---------------- fused MFMA conv + 6^3 pool (LDS-staged A) ------------
// 800 blocks = (n, OD, OH); 576 threads = 9 waves (mdl, mhl)
__global__ __launch_bounds__(576, 4) void conv_mfma(const ushort_t* __restrict__ xT,
                                                    const ushort_t* __restrict__ Btab,
                                                    const float* __restrict__ wsf,
                                                    float* __restrict__ out) {
  __shared__ ushort_t Bl[27 * 64 * 8];    // 27648 B
  __shared__ ushort_t As2[2][5440];       // 2 x 10880 B (one dpad plane: 5h x 34w x 32ic)
  __shared__ float ytile[6 * 6 * 64];     // 9216 B
  __shared__ float red[64];

  int blk = blockIdx.x;
  int OH = blk % 10, OD = (blk / 10) % 5, n = blk / 50;
  int t = threadIdx.x;

  int wv = t >> 6, l = t & 63;
  int mdl = wv / 3, mhl = wv % 3;
  int tt = l & 15, g = l >> 4;
  const ushort_t* xn = xT + (size_t)n * XTN;
  // plane slab for phase p: contiguous 5440 ushorts at ((3OD+p)*34 + 3OH)*1088
  const ushort_t* slab0 = xn + ((size_t)(3 * OD) * 34 + 3 * OH) * ROW_US;

  // ---- stage Btab + plane 0
  for (int s = t; s < 1728; s += 576)
    *(uint4*)&Bl[s * 8] = *(const uint4*)&Btab[s * 8];
  {
    uint4 v0 = *(const uint4*)(slab0 + t * 8);
    uint4 v1;
    if (t < 104) v1 = *(const uint4*)(slab0 + (t + 576) * 8);
    *(uint4*)&As2[0][t * 8] = v0;
    if (t < 104) *(uint4*)&As2[0][(t + 576) * 8] = v1;
  }
  __syncthreads();

  v4f acc0 = {0.f, 0.f, 0.f, 0.f};
  v4f acc1 = {0.f, 0.f, 0.f, 0.f};
  int lane_off = tt * 32 + g * 8;

  for (int p = 0; p < 5; ++p) {
    // ---- T14: issue next plane's global loads early
    uint4 v0, v1;
    if (p < 4) {
      const ushort_t* slab = slab0 + (size_t)(p + 1) * 34 * ROW_US;
      v0 = *(const uint4*)(slab + t * 8);
      if (t < 104) v1 = *(const uint4*)(slab + (t + 576) * 8);
    }

    // ---- compute phase p (wave active if a = mdl+2-p in [0,2])
    int a = mdl + 2 - p;
    if (0 <= a && a <= 2) {
      const ushort_t* Ab = As2[p & 1];
      const ushort_t* Bb = &Bl[(size_t)a * 9 * 64 * 8 + l * 8];
#pragma unroll
      for (int b = 0; b < 3; ++b) {
#pragma unroll
        for (int c = 0; c < 3; ++c) {
          int idx = ((mhl + 2 - b) * 34 + (2 - c)) * 32 + lane_off;
          v8s bv = *(const v8s*)(Bb + (b * 3 + c) * 512);
          v8s a0 = *(const v8s*)&Ab[idx];
          v8s a1 = *(const v8s*)&Ab[idx + 512];
          acc0 = __builtin_amdgcn_mfma_f32_16x16x32_bf16(a0, bv, acc0, 0, 0, 0);
          acc1 = __builtin_amdgcn_mfma_f32_16x16x32_bf16(a1, bv, acc1, 0, 0, 0);
        }
      }
    }

    // ---- write next plane into other buffer, one barrier
    if (p < 4) {
      ushort_t* dst = As2[(p + 1) & 1];
      *(uint4*)&dst[t * 8] = v0;
      if (t < 104) *(uint4*)&dst[(t + 576) * 8] = v1;
      __syncthreads();
    }
  }

  // ---- D scatter to ytile (layout verified R6)
  __syncthreads();
  if (tt < 8) {
    int td = tt & 1, th = (tt >> 1) & 1, tw = tt >> 2;
    int odl = 2 * mdl + td, ohl = 2 * mhl + th;
#pragma unroll
    for (int i = 0; i < 4; ++i) {
      int mwD0 = 4 * g + i;
      ytile[(odl * 6 + ohl) * 64 + 2 * mwD0 + tw] = acc0[i];
      ytile[(odl * 6 + ohl) * 64 + 2 * (16 + mwD0) + tw] = acc1[i];
    }
  }
  __syncthreads();

  if (t < 60) {
    int odl = t / 10, OW = t % 10;
    float m = -3.4e38f;
    for (int oh = 0; oh < 6; ++oh)
#pragma unroll
      for (int j = 0; j < 6; ++j)
        m = fmaxf(m, ytile[(odl * 6 + oh) * 64 + 6 * OW + j]);
    red[t] = m;
  }
  __syncthreads();
  if (t < 10) {
    float m = red[t];
#pragma unroll
    for (int odl = 1; odl < 6; ++odl) m = fmaxf(m, red[odl * 10 + t]);
    out[((n * 5 + OD) * 10 + OH) * 10 + t] = m + wsf[4096];
  }
}

// ================= fallback: R5 verified fp32 path =====================
template<int NCHUNK>
__global__ __launch_bounds__(256, 4) void conv_stage1(const float* __restrict__ x,
                                                      const float* __restrict__ ws,
                                                      float* part, int woff) {
  constexpr int ICPB = 32 / NCHUNK;
  constexpr int NPHS = ICPB / 2;
  __shared__ __align__(16) float xs[170 * XSTR];
  int blk = blockIdx.x;
  int s0 = blk % 320;
  int chunk = blk / 320;
  int wq = s0 & 1, hq = (s0 >> 1) & 1, dc = (s0 >> 2) % 5, n = s0 / 20;
  int t = threadIdx.x;
  int mw = t % 15, lmh = t / 15;
  int id_base = 3 * dc - 1, ih_base = 15 * hq - 1;
  int iwb = wq ? 12 : -4;
  int cb = mw + (wq ? 2 : 3);
  const float* xn = x + (size_t)n * NSTRIDE + (size_t)(chunk * ICPB) * CHSTR;
  const float* wsw = ws + woff + (size_t)(chunk * ICPB) * 128;
  float acc[3][2][2][2] = {{{{0.f}}}};
  for (int phs = 0; phs < NPHS; ++phs) {
    for (int s = t; s < 1700; s += 256) {
      int c2 = s % 10, row = s / 10;
      int bh = row % 17, q = row / 17;
      int ad = q % 5, lic = q / 5;
      int id = id_base + ad, ih = ih_base + bh, iw = iwb + 2 * c2;
      float2 v = make_float2(0.f, 0.f);
      if ((id | ih | iw) >= 0)
        v = *(const float2*)&xn[(size_t)(phs * 2 + lic) * CHSTR + (id * HIN + ih) * WIN + iw];
      *(float2*)&xs[row * XSTR + 2 * c2] = v;
    }
    __syncthreads();
    if (t < 225) {
#pragma unroll
      for (int lic = 0; lic < 2; ++lic) {
        const float* wc = wsw + (size_t)(phs * 2 + lic) * 128;
        const float* xc = &xs[(lic * 85 + lmh) * XSTR + cb];
        float xv[5][3][3];
#pragma unroll
        for (int a = 0; a < 5; ++a)
#pragma unroll
          for (int b = 0; b < 3; ++b) {
            const float* xr = xc + (a * 17 + b) * XSTR;
            xv[a][b][0] = xr[0]; xv[a][b][1] = xr[1]; xv[a][b][2] = xr[2];
          }
#pragma unroll
        for (int kd = 0; kd < 5; ++kd) {
          constexpr int DT[5] = {0, 1, 0, 1, 0};
          constexpr int AOFF[5] = {2, 2, 1, 1, 0};
          const int dt = DT[kd], aoff = AOFF[kd];
          float wv[25];
#pragma unroll
          for (int j = 0; j < 25; ++j) wv[j] = wc[kd * 25 + j];
#pragma unroll
          for (int kh = 0; kh < 5; ++kh) {
            constexpr int HT[5] = {0, 1, 0, 1, 0};
            constexpr int BOFF[5] = {2, 2, 1, 1, 0};
            const int ht = HT[kh], boff = BOFF[kh];
#pragma unroll
            for (int m = 0; m < 3; ++m) {
              const float x0 = xv[m + aoff][boff][0];
              const float x1 = xv[m + aoff][boff][1];
              const float x2 = xv[m + aoff][boff][2];
              acc[m][dt][ht][0] += x0 * wv[kh * 5 + 4];
              acc[m][dt][ht][0] += x1 * wv[kh * 5 + 2];
              acc[m][dt][ht][0] += x2 * wv[kh * 5 + 0];
              acc[m][dt][ht][1] += x1 * wv[kh * 5 + 3];
              acc[m][dt][ht][1] += x2 * wv[kh * 5 + 1];
            }
          }
        }
      }
    }
    __syncthreads();
  }
  if (t < 225) {
    float* pb = part + (size_t)chunk * Y_TOT + (size_t)n * Y_N;
#pragma unroll
    for (int m = 0; m < 3; ++m)
#pragma unroll
      for (int dt = 0; dt < 2; ++dt)
#pragma unroll
        for (int ht = 0; ht < 2; ++ht) {
          int od_g = 6 * dc + 2 * m + dt;
          int oh_g = 30 * hq + 2 * lmh + ht;
          int ow_g = 30 * wq + 2 * mw;
          *(float2*)&pb[(od_g * 60 + oh_g) * 60 + ow_g] =
              make_float2(acc[m][dt][ht][0], acc[m][dt][ht][1]);
        }
  }
}

template<int NCHUNK>
__global__ __launch_bounds__(256) void pool_stage2(const float* __restrict__ part,
                                                   const float* __restrict__ ws,
                                                   float* __restrict__ out, int woff) {
  __shared__ __align__(16) float buf[2160];
  __shared__ float red[240];
  int blk = blockIdx.x;
  int hc = blk % 10, dc = (blk / 10) % 5, n = blk / 50;
  int t = threadIdx.x;
  const float* pb = part + (size_t)n * Y_N;
  for (int s = t; s < 540; s += 256) {
    int row = s / 15, c4 = s % 15;
    int od = row / 6, oh = row % 6;
    size_t idx = (size_t)((6 * dc + od) * 60 + (6 * hc + oh)) * 60 + 4 * c4;
    float4 v = *(const float4*)&pb[idx];
#pragma unroll
    for (int c = 1; c < NCHUNK; ++c) {
      float4 u = *(const float4*)&pb[(size_t)c * Y_TOT + idx];
      v.x += u.x; v.y += u.y; v.z += u.z; v.w += u.w;
    }
    *(float4*)&buf[row * 60 + 4 * c4] = v;
  }
  __syncthreads();
  if (t < 240) {
    int wc = t / 24, sub = t % 24;
    float m = -3.4e38f;
#pragma unroll
    for (int k = 0; k < 9; ++k) {
      int e = sub + 24 * k;
      int od = e / 36, r = e % 36;
      int oh = r / 6, ow0 = r % 6;
      m = fmaxf(m, buf[(od * 6 + oh) * 60 + 6 * wc + ow0]);
    }
    red[t] = m;
  }
  __syncthreads();
  if (t < 10) {
    float mm = -3.4e38f;
#pragma unroll
    for (int s2 = 0; s2 < 24; ++s2) mm = fmaxf(mm, red[t * 24 + s2]);
    out[((n * 5 + dc) * 10 + hc) * 10 + t] = mm + ws[woff + 4096];
  }
}

__global__ __launch_bounds__(128) void prep2(const float* __restrict__ w,
                                             const float* __restrict__ bias,
                                             float* __restrict__ ws, int woff) {
  int i = blockIdx.x, t = threadIdx.x;
  if (t < 125) {
    const float* wp = w + (size_t)i * 64 * 125 + t;
    float v = 0.f;
#pragma unroll
    for (int o = 0; o < 64; ++o) v += wp[o * 125];
    ws[woff + i * 128 + t] = v;
  }
  if (i == 0 && t == 126) {
    float b = 0.f;
    for (int o = 0; o < 64; ++o) b += bias[o];
    ws[woff + 4096] = b;
  }
}

// ---------------- launch ----------------------------------------------
extern "C" void kernel_launch(void* const* d_in, const int* in_sizes, int n_in,
                              void* d_out, int out_size, void* d_ws, size_t ws_size,
                              hipStream_t stream) {
  const float* x    = (const float*)d_in[0];
  const float* w    = (const float*)d_in[1];
  const float* bias = (const float*)d_in[2];
  float* outp = (float*)d_out;

  if (ws_size >= (size_t)NEED_MFMA) {
    ushort_t* xT = (ushort_t*)d_ws;
    ushort_t* Bt = (ushort_t*)((char*)d_ws + BT_BYTE_OFF);
    float* wsf   = (float*)((char*)d_ws + WSF_BYTE_OFF);
    prep_w<<<32, 128, 0, stream>>>(w, bias, wsf);
    prep_b<<<27, 64, 0, stream>>>(wsf, Bt);
    transpose_x<<<16 * 18 * 4, 256, 0, stream>>>(x, xT);
    conv_mfma<<<800, 576, 0, stream>>>(xT, Bt, wsf, outp);
    return;
  }

  float* ws = (float*)d_ws;
  const size_t need4 = ((size_t)4 * Y_TOT + 4097) * 4;
  const size_t need2 = ((size_t)2 * Y_TOT + 4097) * 4;
  const size_t need1 = ((size_t)1 * Y_TOT + 4097) * 4;
  if (ws_size >= need4) {
    int woff = 4 * Y_TOT;
    prep2<<<32, 128, 0, stream>>>(w, bias, ws, woff);
    conv_stage1<4><<<320 * 4, 256, 0, stream>>>(x, ws, ws, woff);
    pool_stage2<4><<<800, 256, 0, stream>>>(ws, ws, outp, woff);
  } else if (ws_size >= need2) {
    int woff = 2 * Y_TOT;
    prep2<<<32, 128, 0, stream>>>(w, bias, ws, woff);
    conv_stage1<2><<<320 * 2, 256, 0, stream>>>(x, ws, ws, woff);
    pool_stage2<2><<<800, 256, 0, stream>>>(ws, ws, outp, woff);
  } else if (ws_size >= need1) {
    int woff = 1 * Y_TOT;
    prep2<<<32, 128, 0, stream>>>(w, bias, ws, woff);
    conv_stage1<1><<<320 * 1, 256, 0, stream>>>(x, ws, ws, woff);
    pool_stage2<1><<<800, 256, 0, stream>>>(ws, ws, outp, woff);
  }
}

// Round 8
// 40.659 us; speedup vs baseline: 2.8506x; 1.0810x over previous
//
#include <hip/hip_runtime.h>

// y = convT3d(x, weight.sum(oc), stride=2, pad=2, k=5) + sum(bias); out = 6^3 stride-6 max.
// MFMA formulation (verified R6/R7, absmax 0.25): y[2m+t] = sum_{ic,abc} x[ic,m+1-abc]*w[ic,t+2abc]
//   D[16 w-cells x 8 parities] += A[cells x 32ic] * B[32ic x parities], 27 (a,b,c) chunks.
// xT: bf16 [n][dpad 18][hpad 34][wpad 34][ic 32], halos zeroed (only dpad 0..16, hpad 0..31 written).
// R8: conv LDS overlay (ytile->As1, red->Bl) 58.9->49.4KB => 3 blocks/CU; prep merged into one
//     kernel (tap->abc is a bijection); transpose skips never-read slices.

typedef short v8s __attribute__((ext_vector_type(8)));
typedef float v4f __attribute__((ext_vector_type(4)));
typedef unsigned short ushort_t;

#define DIN 16
#define HIN 32
#define WIN 32
#define CHSTR (DIN*HIN*WIN)      // 16384
#define NSTRIDE (32*CHSTR)
#define Y_N 108000
#define Y_TOT (16*Y_N)
#define XSTR 24

#define XT_US 10653696u          // 16*18*34*34*32 ushorts
#define XTN   665856u            // per-n: 18*34*34*32
#define PLANE_US 36992u          // 34*34*32
#define ROW_US 1088u             // 34*32
#define BT_BYTE_OFF 21307392u    // XT_US*2
#define WSF_BYTE_OFF 21335040u   // +27*64*8*2
#define NEED_MFMA (21335040u + 4097u*4u)

static __device__ __forceinline__ ushort_t f2bf(float f) {
  unsigned u = __builtin_bit_cast(unsigned, f);
  unsigned r = (u + 0x7FFFu + ((u >> 16) & 1u)) >> 16;
  return (ushort_t)r;
}

// ---------------- merged prep: B fragment table + bias sum -------------
// Each tap (kd,kh,kw) belongs to exactly one (a,b,c)=((kd-td)/2,...) -> compute
// Btab directly from raw w. 27 blocks x 256 threads; thread = (lane l, j-pair).
__global__ __launch_bounds__(256) void prep_bw(const float* __restrict__ w,
                                               const float* __restrict__ bias,
                                               ushort_t* __restrict__ Btab,
                                               float* __restrict__ wsf) {
  int abc = blockIdx.x;               // a*9 + b*3 + c
  int a = abc / 9, b = (abc / 3) % 3, c = abc % 3;
  int t = threadIdx.x;
  int half = t & 3;                   // j-pair 2*half, 2*half+1
  int l = t >> 2;                     // lane 0..63
  int tt = l & 15, g = l >> 4;
  float v0 = 0.f, v1 = 0.f;
  if (tt < 8) {
    int td = tt & 1, th = (tt >> 1) & 1, tw = tt >> 2;
    int kd = td + 2 * a, kh = th + 2 * b, kw = tw + 2 * c;
    if (kd < 5 && kh < 5 && kw < 5) {
      int off = kd * 25 + kh * 5 + kw;
      const float* wp0 = w + (size_t)(8 * g + 2 * half) * 64 * 125 + off;
      const float* wp1 = wp0 + 64 * 125;
      float s0 = 0.f, s1 = 0.f;
#pragma unroll
      for (int oc = 0; oc < 64; ++oc) { s0 += wp0[oc * 125]; s1 += wp1[oc * 125]; }
      v0 = s0; v1 = s1;
    }
  }
  unsigned pk = (unsigned)f2bf(v0) | ((unsigned)f2bf(v1) << 16);
  ((unsigned*)Btab)[(abc * 64 + l) * 4 + half] = pk;
  if (abc == 0 && t == 0) {
    float bsum = 0.f;
    for (int o = 0; o < 64; ++o) bsum += bias[o];
    wsf[4096] = bsum;
  }
}

// ---------------- transpose x -> xT bf16 (only read slices) ------------
// grid: n(16) x dpad(17) x hq(4); 8 hpad rows each (rows 0..31; 32/33 never read)
__global__ __launch_bounds__(256) void transpose_x(const float* __restrict__ x,
                                                   ushort_t* __restrict__ xT) {
  int blk = blockIdx.x;
  int hq = blk & 3;
  int dpad = (blk >> 2) % 17;
  int n = blk / 68;
  int t = threadIdx.x;
  int h0 = 8 * hq;
  ushort_t* plane = xT + (size_t)(n * 18 + dpad) * PLANE_US;
  int d = dpad - 1;

  if (d < 0) {                         // dpad==0 -> zero slice
    for (int r = 0; r < 8; ++r) {
      char* row = (char*)(plane + (size_t)(h0 + r) * ROW_US);
      for (int s = t; s < 136; s += 256)
        *(uint4*)(row + s * 16) = make_uint4(0, 0, 0, 0);
    }
    return;
  }

  __shared__ float lb[2][32 * 33];
  const float* xb = x + ((size_t)n * 32 * 16 + d) * 1024;
  int ic = t >> 3, wq = t & 7;

  {
    int h = h0 - 1;
    if (h >= 0) {                      // h<=30 provable
      float4 v = *(const float4*)&xb[(size_t)ic * 16384 + h * 32 + wq * 4];
      float* L = lb[0] + ic * 33 + wq * 4;
      L[0] = v.x; L[1] = v.y; L[2] = v.z; L[3] = v.w;
    }
  }
  int pp = 0;
  for (int i = 0; i < 8; ++i) {
    __syncthreads();
    if (i + 1 < 8) {
      int h = h0 + i;                  // next iter's h
      if (h <= 31) {
        float4 v = *(const float4*)&xb[(size_t)ic * 16384 + h * 32 + wq * 4];
        float* L = lb[pp ^ 1] + ic * 33 + wq * 4;
        L[0] = v.x; L[1] = v.y; L[2] = v.z; L[3] = v.w;
      }
    }
    int h = h0 + i - 1;
    ushort_t* row = plane + (size_t)(h0 + i) * ROW_US;
    bool hv = (h >= 0 && h <= 31);
    for (int s = t; s < 272; s += 256) {
      int wslot = s >> 3, q = s & 7;
      ushort_t o0 = 0, o1 = 0, o2 = 0, o3 = 0;
      if (wslot >= 1 && wslot <= 32 && hv) {
        int w = wslot - 1;
        const float* L = lb[pp];
        o0 = f2bf(L[(4 * q + 0) * 33 + w]);
        o1 = f2bf(L[(4 * q + 1) * 33 + w]);
        o2 = f2bf(L[(4 * q + 2) * 33 + w]);
        o3 = f2bf(L[(4 * q + 3) * 33 + w]);
      }
      uint2 pk;
      pk.x = (unsigned)o0 | ((unsigned)o1 << 16);
      pk.y = (unsigned)o2 | ((unsigned)o3 << 16);
      *(uint2*)(row + wslot * 32 + q * 4) = pk;
    }
    pp ^= 1;
  }
}

// ---------------- fused MFMA conv + 6^3 pool (LDS-staged A, overlay) ----
// 800 blocks = (n, OD, OH); 576 threads = 9 waves (mdl, mhl)
__global__ __launch_bounds__(576, 7) void conv_mfma(const ushort_t* __restrict__ xT,
                                                    const ushort_t* __restrict__ Btab,
                                                    const float* __restrict__ wsf,
                                                    float* __restrict__ out) {
  __shared__ __align__(16) char smem[49408];
  ushort_t* Bl  = (ushort_t*)smem;              // 27648 B; red overlays (dead after MFMAs)
  ushort_t* As0 = (ushort_t*)(smem + 27648);    // 10880 B
  ushort_t* As1 = (ushort_t*)(smem + 38528);    // 10880 B; ytile overlays (dead after p=3)
  float* ytile  = (float*)(smem + 38528);       // 9216 B
  float* red    = (float*)smem;                 // 256 B

  int blk = blockIdx.x;
  int OH = blk % 10, OD = (blk / 10) % 5, n = blk / 50;
  int t = threadIdx.x;

  int wv = t >> 6, l = t & 63;
  int mdl = wv / 3, mhl = wv % 3;
  int tt = l & 15, g = l >> 4;
  const ushort_t* xn = xT + (size_t)n * XTN;
  // plane slab for phase p: contiguous 5440 ushorts at ((3OD+p)*34 + 3OH)*1088
  const ushort_t* slab0 = xn + ((size_t)(3 * OD) * 34 + 3 * OH) * ROW_US;

  // ---- stage Btab + plane 0
  for (int s = t; s < 1728; s += 576)
    *(uint4*)&Bl[s * 8] = *(const uint4*)&Btab[s * 8];
  {
    uint4 v0 = *(const uint4*)(slab0 + t * 8);
    uint4 v1;
    if (t < 104) v1 = *(const uint4*)(slab0 + (t + 576) * 8);
    *(uint4*)&As0[t * 8] = v0;
    if (t < 104) *(uint4*)&As0[(t + 576) * 8] = v1;
  }
  __syncthreads();

  v4f acc0 = {0.f, 0.f, 0.f, 0.f};
  v4f acc1 = {0.f, 0.f, 0.f, 0.f};
  int lane_off = tt * 32 + g * 8;

  for (int p = 0; p < 5; ++p) {
    // ---- T14: issue next plane's global loads early
    uint4 v0, v1;
    if (p < 4) {
      const ushort_t* slab = slab0 + (size_t)(p + 1) * 34 * ROW_US;
      v0 = *(const uint4*)(slab + t * 8);
      if (t < 104) v1 = *(const uint4*)(slab + (t + 576) * 8);
    }

    // ---- compute phase p (wave active if a = mdl+2-p in [0,2])
    int a = mdl + 2 - p;
    if (0 <= a && a <= 2) {
      const ushort_t* Ab = (p & 1) ? As1 : As0;
      const ushort_t* Bb = &Bl[(size_t)a * 9 * 64 * 8 + l * 8];
#pragma unroll
      for (int b = 0; b < 3; ++b) {
#pragma unroll
        for (int c = 0; c < 3; ++c) {
          int idx = ((mhl + 2 - b) * 34 + (2 - c)) * 32 + lane_off;
          v8s bv = *(const v8s*)(Bb + (b * 3 + c) * 512);
          v8s a0 = *(const v8s*)&Ab[idx];
          v8s a1 = *(const v8s*)&Ab[idx + 512];
          acc0 = __builtin_amdgcn_mfma_f32_16x16x32_bf16(a0, bv, acc0, 0, 0, 0);
          acc1 = __builtin_amdgcn_mfma_f32_16x16x32_bf16(a1, bv, acc1, 0, 0, 0);
        }
      }
    }

    // ---- write next plane into other buffer, one barrier
    if (p < 4) {
      ushort_t* dst = (p & 1) ? As0 : As1;     // (p+1)&1
      *(uint4*)&dst[t * 8] = v0;
      if (t < 104) *(uint4*)&dst[(t + 576) * 8] = v1;
      __syncthreads();
    }
  }

  // ---- D scatter to ytile (layout verified R6); ytile overlays As1 (dead)
  __syncthreads();
  if (tt < 8) {
    int td = tt & 1, th = (tt >> 1) & 1, tw = tt >> 2;
    int odl = 2 * mdl + td, ohl = 2 * mhl + th;
#pragma unroll
    for (int i = 0; i < 4; ++i) {
      int mwD0 = 4 * g + i;
      ytile[(odl * 6 + ohl) * 64 + 2 * mwD0 + tw] = acc0[i];
      ytile[(odl * 6 + ohl) * 64 + 2 * (16 + mwD0) + tw] = acc1[i];
    }
  }
  __syncthreads();

  if (t < 60) {
    int odl = t / 10, OW = t % 10;
    float m = -3.4e38f;
    for (int oh = 0; oh < 6; ++oh)
#pragma unroll
      for (int j = 0; j < 6; ++j)
        m = fmaxf(m, ytile[(odl * 6 + oh) * 64 + 6 * OW + j]);
    red[t] = m;
  }
  __syncthreads();
  if (t < 10) {
    float m = red[t];
#pragma unroll
    for (int odl = 1; odl < 6; ++odl) m = fmaxf(m, red[odl * 10 + t]);
    out[((n * 5 + OD) * 10 + OH) * 10 + t] = m + wsf[4096];
  }
}

// ================= fallback: R5 verified fp32 path =====================
template<int NCHUNK>
__global__ __launch_bounds__(256, 4) void conv_stage1(const float* __restrict__ x,
                                                      const float* __restrict__ ws,
                                                      float* part, int woff) {
  constexpr int ICPB = 32 / NCHUNK;
  constexpr int NPHS = ICPB / 2;
  __shared__ __align__(16) float xs[170 * XSTR];
  int blk = blockIdx.x;
  int s0 = blk % 320;
  int chunk = blk / 320;
  int wq = s0 & 1, hq = (s0 >> 1) & 1, dc = (s0 >> 2) % 5, n = s0 / 20;
  int t = threadIdx.x;
  int mw = t % 15, lmh = t / 15;
  int id_base = 3 * dc - 1, ih_base = 15 * hq - 1;
  int iwb = wq ? 12 : -4;
  int cb = mw + (wq ? 2 : 3);
  const float* xn = x + (size_t)n * NSTRIDE + (size_t)(chunk * ICPB) * CHSTR;
  const float* wsw = ws + woff + (size_t)(chunk * ICPB) * 128;
  float acc[3][2][2][2] = {{{{0.f}}}};
  for (int phs = 0; phs < NPHS; ++phs) {
    for (int s = t; s < 1700; s += 256) {
      int c2 = s % 10, row = s / 10;
      int bh = row % 17, q = row / 17;
      int ad = q % 5, lic = q / 5;
      int id = id_base + ad, ih = ih_base + bh, iw = iwb + 2 * c2;
      float2 v = make_float2(0.f, 0.f);
      if ((id | ih | iw) >= 0)
        v = *(const float2*)&xn[(size_t)(phs * 2 + lic) * CHSTR + (id * HIN + ih) * WIN + iw];
      *(float2*)&xs[row * XSTR + 2 * c2] = v;
    }
    __syncthreads();
    if (t < 225) {
#pragma unroll
      for (int lic = 0; lic < 2; ++lic) {
        const float* wc = wsw + (size_t)(phs * 2 + lic) * 128;
        const float* xc = &xs[(lic * 85 + lmh) * XSTR + cb];
        float xv[5][3][3];
#pragma unroll
        for (int a = 0; a < 5; ++a)
#pragma unroll
          for (int b = 0; b < 3; ++b) {
            const float* xr = xc + (a * 17 + b) * XSTR;
            xv[a][b][0] = xr[0]; xv[a][b][1] = xr[1]; xv[a][b][2] = xr[2];
          }
#pragma unroll
        for (int kd = 0; kd < 5; ++kd) {
          constexpr int DT[5] = {0, 1, 0, 1, 0};
          constexpr int AOFF[5] = {2, 2, 1, 1, 0};
          const int dt = DT[kd], aoff = AOFF[kd];
          float wv[25];
#pragma unroll
          for (int j = 0; j < 25; ++j) wv[j] = wc[kd * 25 + j];
#pragma unroll
          for (int kh = 0; kh < 5; ++kh) {
            constexpr int HT[5] = {0, 1, 0, 1, 0};
            constexpr int BOFF[5] = {2, 2, 1, 1, 0};
            const int ht = HT[kh], boff = BOFF[kh];
#pragma unroll
            for (int m = 0; m < 3; ++m) {
              const float x0 = xv[m + aoff][boff][0];
              const float x1 = xv[m + aoff][boff][1];
              const float x2 = xv[m + aoff][boff][2];
              acc[m][dt][ht][0] += x0 * wv[kh * 5 + 4];
              acc[m][dt][ht][0] += x1 * wv[kh * 5 + 2];
              acc[m][dt][ht][0] += x2 * wv[kh * 5 + 0];
              acc[m][dt][ht][1] += x1 * wv[kh * 5 + 3];
              acc[m][dt][ht][1] += x2 * wv[kh * 5 + 1];
            }
          }
        }
      }
    }
    __syncthreads();
  }
  if (t < 225) {
    float* pb = part + (size_t)chunk * Y_TOT + (size_t)n * Y_N;
#pragma unroll
    for (int m = 0; m < 3; ++m)
#pragma unroll
      for (int dt = 0; dt < 2; ++dt)
#pragma unroll
        for (int ht = 0; ht < 2; ++ht) {
          int od_g = 6 * dc + 2 * m + dt;
          int oh_g = 30 * hq + 2 * lmh + ht;
          int ow_g = 30 * wq + 2 * mw;
          *(float2*)&pb[(od_g * 60 + oh_g) * 60 + ow_g] =
              make_float2(acc[m][dt][ht][0], acc[m][dt][ht][1]);
        }
  }
}

template<int NCHUNK>
__global__ __launch_bounds__(256) void pool_stage2(const float* __restrict__ part,
                                                   const float* __restrict__ ws,
                                                   float* __restrict__ out, int woff) {
  __shared__ __align__(16) float buf[2160];
  __shared__ float red[240];
  int blk = blockIdx.x;
  int hc = blk % 10, dc = (blk / 10) % 5, n = blk / 50;
  int t = threadIdx.x;
  const float* pb = part + (size_t)n * Y_N;
  for (int s = t; s < 540; s += 256) {
    int row = s / 15, c4 = s % 15;
    int od = row / 6, oh = row % 6;
    size_t idx = (size_t)((6 * dc + od) * 60 + (6 * hc + oh)) * 60 + 4 * c4;
    float4 v = *(const float4*)&pb[idx];
#pragma unroll
    for (int c = 1; c < NCHUNK; ++c) {
      float4 u = *(const float4*)&pb[(size_t)c * Y_TOT + idx];
      v.x += u.x; v.y += u.y; v.z += u.z; v.w += u.w;
    }
    *(float4*)&buf[row * 60 + 4 * c4] = v;
  }
  __syncthreads();
  if (t < 240) {
    int wc = t / 24, sub = t % 24;
    float m = -3.4e38f;
#pragma unroll
    for (int k = 0; k < 9; ++k) {
      int e = sub + 24 * k;
      int od = e / 36, r = e % 36;
      int oh = r / 6, ow0 = r % 6;
      m = fmaxf(m, buf[(od * 6 + oh) * 60 + 6 * wc + ow0]);
    }
    red[t] = m;
  }
  __syncthreads();
  if (t < 10) {
    float mm = -3.4e38f;
#pragma unroll
    for (int s2 = 0; s2 < 24; ++s2) mm = fmaxf(mm, red[t * 24 + s2]);
    out[((n * 5 + dc) * 10 + hc) * 10 + t] = mm + ws[woff + 4096];
  }
}

__global__ __launch_bounds__(128) void prep2(const float* __restrict__ w,
                                             const float* __restrict__ bias,
                                             float* __restrict__ ws, int woff) {
  int i = blockIdx.x, t = threadIdx.x;
  if (t < 125) {
    const float* wp = w + (size_t)i * 64 * 125 + t;
    float v = 0.f;
#pragma unroll
    for (int o = 0; o < 64; ++o) v += wp[o * 125];
    ws[woff + i * 128 + t] = v;
  }
  if (i == 0 && t == 126) {
    float b = 0.f;
    for (int o = 0; o < 64; ++o) b += bias[o];
    ws[woff + 4096] = b;
  }
}

// ---------------- launch ----------------------------------------------
extern "C" void kernel_launch(void* const* d_in, const int* in_sizes, int n_in,
                              void* d_out, int out_size, void* d_ws, size_t ws_size,
                              hipStream_t stream) {
  const float* x    = (const float*)d_in[0];
  const float* w    = (const float*)d_in[1];
  const float* bias = (const float*)d_in[2];
  float* outp = (float*)d_out;

  if (ws_size >= (size_t)NEED_MFMA) {
    ushort_t* xT = (ushort_t*)d_ws;
    ushort_t* Bt = (ushort_t*)((char*)d_ws + BT_BYTE_OFF);
    float* wsf   = (float*)((char*)d_ws + WSF_BYTE_OFF);
    prep_bw<<<27, 256, 0, stream>>>(w, bias, Bt, wsf);
    transpose_x<<<16 * 17 * 4, 256, 0, stream>>>(x, xT);
    conv_mfma<<<800, 576, 0, stream>>>(xT, Bt, wsf, outp);
    return;
  }

  float* ws = (float*)d_ws;
  const size_t need4 = ((size_t)4 * Y_TOT + 4097) * 4;
  const size_t need2 = ((size_t)2 * Y_TOT + 4097) * 4;
  const size_t need1 = ((size_t)1 * Y_TOT + 4097) * 4;
  if (ws_size >= need4) {
    int woff = 4 * Y_TOT;
    prep2<<<32, 128, 0, stream>>>(w, bias, ws, woff);
    conv_stage1<4><<<320 * 4, 256, 0, stream>>>(x, ws, ws, woff);
    pool_stage2<4><<<800, 256, 0, stream>>>(ws, ws, outp, woff);
  } else if (ws_size >= need2) {
    int woff = 2 * Y_TOT;
    prep2<<<32, 128, 0, stream>>>(w, bias, ws, woff);
    conv_stage1<2><<<320 * 2, 256, 0, stream>>>(x, ws, ws, woff);
    pool_stage2<2><<<800, 256, 0, stream>>>(ws, ws, outp, woff);
  } else if (ws_size >= need1) {
    int woff = 1 * Y_TOT;
    prep2<<<32, 128, 0, stream>>>(w, bias, ws, woff);
    conv_stage1<1><<<320 * 1, 256, 0, stream>>>(x, ws, ws, woff);
    pool_stage2<1><<<800, 256, 0, stream>>>(ws, ws, outp, woff);
  }
}

// Round 9
// 36.078 us; speedup vs baseline: 3.2126x; 1.1270x over previous
//
#include <hip/hip_runtime.h>

// y = convT3d(x, weight.sum(oc), stride=2, pad=2, k=5) + sum(bias); out = 6^3 stride-6 max.
// MFMA formulation (verified R6-R8, absmax 0.25): y[2m+t] = sum_{ic,abc} x[ic,m+1-abc]*w[ic,t+2abc]
//   D[16 w-cells x 8 parities] += A[cells x 32ic] * B[32ic x parities], 27 (a,b,c) chunks.
// xT: bf16 [n][dpad 18][hpad 34][wpad 34][ic 32], halos zeroed (dpad 0..16, hpad 0..31 written).
// R9: B-frags read DIRECTLY from global Btab (L2-hot; each frag used once per wave -> LDS staging
//     bought nothing). Conv LDS reads/wave-phase 27->18; LDS 31KB, no overlays. Transpose stores
//     widened to 16B; prep folded into transpose grid (blk >= 1088).

typedef short v8s __attribute__((ext_vector_type(8)));
typedef float v4f __attribute__((ext_vector_type(4)));
typedef unsigned short ushort_t;

#define DIN 16
#define HIN 32
#define WIN 32
#define CHSTR (DIN*HIN*WIN)      // 16384
#define NSTRIDE (32*CHSTR)
#define Y_N 108000
#define Y_TOT (16*Y_N)
#define XSTR 24

#define XT_US 10653696u          // 16*18*34*34*32 ushorts
#define XTN   665856u            // per-n: 18*34*34*32
#define PLANE_US 36992u          // 34*34*32
#define ROW_US 1088u             // 34*32
#define BT_BYTE_OFF 21307392u    // XT_US*2
#define WSF_BYTE_OFF 21335040u   // +27*64*8*2
#define NEED_MFMA (21335040u + 4097u*4u)

static __device__ __forceinline__ ushort_t f2bf(float f) {
  unsigned u = __builtin_bit_cast(unsigned, f);
  unsigned r = (u + 0x7FFFu + ((u >> 16) & 1u)) >> 16;
  return (ushort_t)r;
}

// ---------------- transpose x -> xT bf16  (+ folded prep for blk>=1088) --
// blk < 1088: n(16) x dpad(17) x hq(4); 8 hpad rows each (rows 32/33 never read).
// blk >= 1088: abc = blk-1088; build B fragment table from raw w + bias sum.
__global__ __launch_bounds__(256) void transpose_x(const float* __restrict__ x,
                                                   const float* __restrict__ w,
                                                   const float* __restrict__ bias,
                                                   ushort_t* __restrict__ xT,
                                                   ushort_t* __restrict__ Btab,
                                                   float* __restrict__ wsf) {
  int blk = blockIdx.x;
  int t = threadIdx.x;

  if (blk >= 1088) {            // ---- prep path: B table from raw w
    int abc = blk - 1088;       // a*9 + b*3 + c
    int a = abc / 9, b = (abc / 3) % 3, c = abc % 3;
    int half = t & 3;           // j-pair 2*half, 2*half+1
    int l = t >> 2;             // lane 0..63
    int tt = l & 15, g = l >> 4;
    float v0 = 0.f, v1 = 0.f;
    if (tt < 8) {
      int td = tt & 1, th = (tt >> 1) & 1, tw = tt >> 2;
      int kd = td + 2 * a, kh = th + 2 * b, kw = tw + 2 * c;
      if (kd < 5 && kh < 5 && kw < 5) {
        int off = kd * 25 + kh * 5 + kw;
        const float* wp0 = w + (size_t)(8 * g + 2 * half) * 64 * 125 + off;
        const float* wp1 = wp0 + 64 * 125;
        float s0 = 0.f, s1 = 0.f;
#pragma unroll
        for (int oc = 0; oc < 64; ++oc) { s0 += wp0[oc * 125]; s1 += wp1[oc * 125]; }
        v0 = s0; v1 = s1;
      }
    }
    unsigned pk = (unsigned)f2bf(v0) | ((unsigned)f2bf(v1) << 16);
    ((unsigned*)Btab)[(abc * 64 + l) * 4 + half] = pk;
    if (abc == 0 && t == 0) {
      float bsum = 0.f;
      for (int o = 0; o < 64; ++o) bsum += bias[o];
      wsf[4096] = bsum;
    }
    return;
  }

  int hq = blk & 3;
  int dpad = (blk >> 2) % 17;
  int n = blk / 68;
  int h0 = 8 * hq;
  ushort_t* plane = xT + (size_t)(n * 18 + dpad) * PLANE_US;
  int d = dpad - 1;

  if (d < 0) {                         // dpad==0 -> zero slice
    for (int r = 0; r < 8; ++r) {
      char* row = (char*)(plane + (size_t)(h0 + r) * ROW_US);
      for (int s = t; s < 136; s += 256)
        *(uint4*)(row + s * 16) = make_uint4(0, 0, 0, 0);
    }
    return;
  }

  __shared__ float lb[2][32 * 33];
  const float* xb = x + ((size_t)n * 32 * 16 + d) * 1024;
  int ic = t >> 3, wq = t & 7;

  {
    int h = h0 - 1;
    if (h >= 0) {
      float4 v = *(const float4*)&xb[(size_t)ic * 16384 + h * 32 + wq * 4];
      float* L = lb[0] + ic * 33 + wq * 4;
      L[0] = v.x; L[1] = v.y; L[2] = v.z; L[3] = v.w;
    }
  }
  int pp = 0;
  for (int i = 0; i < 8; ++i) {
    __syncthreads();
    if (i + 1 < 8) {
      int h = h0 + i;
      if (h <= 31) {
        float4 v = *(const float4*)&xb[(size_t)ic * 16384 + h * 32 + wq * 4];
        float* L = lb[pp ^ 1] + ic * 33 + wq * 4;
        L[0] = v.x; L[1] = v.y; L[2] = v.z; L[3] = v.w;
      }
    }
    int h = h0 + i - 1;
    ushort_t* row = plane + (size_t)(h0 + i) * ROW_US;
    bool hv = (h >= 0 && h <= 31);
    for (int s = t; s < 136; s += 256) {
      int wslot = s >> 2, q4 = s & 3;        // 16B chunk: ic 8q4..8q4+7
      ushort_t o[8];
#pragma unroll
      for (int j = 0; j < 8; ++j) o[j] = 0;
      if (wslot >= 1 && wslot <= 32 && hv) {
        int w2 = wslot - 1;
        const float* L = lb[pp];
#pragma unroll
        for (int j = 0; j < 8; ++j) o[j] = f2bf(L[(8 * q4 + j) * 33 + w2]);
      }
      uint4 pk;
      pk.x = (unsigned)o[0] | ((unsigned)o[1] << 16);
      pk.y = (unsigned)o[2] | ((unsigned)o[3] << 16);
      pk.z = (unsigned)o[4] | ((unsigned)o[5] << 16);
      pk.w = (unsigned)o[6] | ((unsigned)o[7] << 16);
      *(uint4*)(row + wslot * 32 + q4 * 8) = pk;
    }
    pp ^= 1;
  }
}

// ---------------- fused MFMA conv + 6^3 pool (LDS A, global B) ----------
// 800 blocks = (n, OD, OH); 576 threads = 9 waves (mdl, mhl)
__global__ __launch_bounds__(576, 7) void conv_mfma(const ushort_t* __restrict__ xT,
                                                    const ushort_t* __restrict__ Btab,
                                                    const float* __restrict__ wsf,
                                                    float* __restrict__ out) {
  __shared__ __align__(16) ushort_t As0[5440];   // one dpad plane: 5h x 34w x 32ic
  __shared__ __align__(16) ushort_t As1[5440];
  __shared__ float ytile[6 * 6 * 64];
  __shared__ float red[64];

  int blk = blockIdx.x;
  int OH = blk % 10, OD = (blk / 10) % 5, n = blk / 50;
  int t = threadIdx.x;

  int wv = t >> 6, l = t & 63;
  int mdl = wv / 3, mhl = wv % 3;
  int tt = l & 15, g = l >> 4;
  const ushort_t* xn = xT + (size_t)n * XTN;
  // plane slab for phase p: contiguous 5440 ushorts at ((3OD+p)*34 + 3OH)*1088
  const ushort_t* slab0 = xn + ((size_t)(3 * OD) * 34 + 3 * OH) * ROW_US;

  // ---- stage plane 0
  {
    uint4 v0 = *(const uint4*)(slab0 + t * 8);
    uint4 v1;
    if (t < 104) v1 = *(const uint4*)(slab0 + (t + 576) * 8);
    *(uint4*)&As0[t * 8] = v0;
    if (t < 104) *(uint4*)&As0[(t + 576) * 8] = v1;
  }
  __syncthreads();

  v4f acc0 = {0.f, 0.f, 0.f, 0.f};
  v4f acc1 = {0.f, 0.f, 0.f, 0.f};
  int lane_off = tt * 32 + g * 8;

  for (int p = 0; p < 5; ++p) {
    // ---- T14: issue next plane's global loads early
    uint4 v0, v1;
    if (p < 4) {
      const ushort_t* slab = slab0 + (size_t)(p + 1) * 34 * ROW_US;
      v0 = *(const uint4*)(slab + t * 8);
      if (t < 104) v1 = *(const uint4*)(slab + (t + 576) * 8);
    }

    // ---- compute phase p (wave active if a = mdl+2-p in [0,2])
    int a = mdl + 2 - p;
    if (0 <= a && a <= 2) {
      const ushort_t* Ab = (p & 1) ? As1 : As0;
      const ushort_t* Bg = Btab + ((size_t)a * 9 * 64 + l) * 8;   // global, L2-hot
#pragma unroll
      for (int b = 0; b < 3; ++b) {
#pragma unroll
        for (int c = 0; c < 3; ++c) {
          int idx = ((mhl + 2 - b) * 34 + (2 - c)) * 32 + lane_off;
          v8s bv = *(const v8s*)(Bg + (b * 3 + c) * 512);
          v8s a0 = *(const v8s*)&Ab[idx];
          v8s a1 = *(const v8s*)&Ab[idx + 512];
          acc0 = __builtin_amdgcn_mfma_f32_16x16x32_bf16(a0, bv, acc0, 0, 0, 0);
          acc1 = __builtin_amdgcn_mfma_f32_16x16x32_bf16(a1, bv, acc1, 0, 0, 0);
        }
      }
    }

    // ---- write next plane into other buffer, one barrier
    if (p < 4) {
      ushort_t* dst = (p & 1) ? As0 : As1;     // (p+1)&1
      *(uint4*)&dst[t * 8] = v0;
      if (t < 104) *(uint4*)&dst[(t + 576) * 8] = v1;
      __syncthreads();
    }
  }

  // ---- D scatter to ytile (layout verified R6)
  __syncthreads();
  if (tt < 8) {
    int td = tt & 1, th = (tt >> 1) & 1, tw = tt >> 2;
    int odl = 2 * mdl + td, ohl = 2 * mhl + th;
#pragma unroll
    for (int i = 0; i < 4; ++i) {
      int mwD0 = 4 * g + i;
      ytile[(odl * 6 + ohl) * 64 + 2 * mwD0 + tw] = acc0[i];
      ytile[(odl * 6 + ohl) * 64 + 2 * (16 + mwD0) + tw] = acc1[i];
    }
  }
  __syncthreads();

  if (t < 60) {
    int odl = t / 10, OW = t % 10;
    float m = -3.4e38f;
    for (int oh = 0; oh < 6; ++oh)
#pragma unroll
      for (int j = 0; j < 6; ++j)
        m = fmaxf(m, ytile[(odl * 6 + oh) * 64 + 6 * OW + j]);
    red[t] = m;
  }
  __syncthreads();
  if (t < 10) {
    float m = red[t];
#pragma unroll
    for (int odl = 1; odl < 6; ++odl) m = fmaxf(m, red[odl * 10 + t]);
    out[((n * 5 + OD) * 10 + OH) * 10 + t] = m + wsf[4096];
  }
}

// ================= fallback: R5 verified fp32 path =====================
template<int NCHUNK>
__global__ __launch_bounds__(256, 4) void conv_stage1(const float* __restrict__ x,
                                                      const float* __restrict__ ws,
                                                      float* part, int woff) {
  constexpr int ICPB = 32 / NCHUNK;
  constexpr int NPHS = ICPB / 2;
  __shared__ __align__(16) float xs[170 * XSTR];
  int blk = blockIdx.x;
  int s0 = blk % 320;
  int chunk = blk / 320;
  int wq = s0 & 1, hq = (s0 >> 1) & 1, dc = (s0 >> 2) % 5, n = s0 / 20;
  int t = threadIdx.x;
  int mw = t % 15, lmh = t / 15;
  int id_base = 3 * dc - 1, ih_base = 15 * hq - 1;
  int iwb = wq ? 12 : -4;
  int cb = mw + (wq ? 2 : 3);
  const float* xn = x + (size_t)n * NSTRIDE + (size_t)(chunk * ICPB) * CHSTR;
  const float* wsw = ws + woff + (size_t)(chunk * ICPB) * 128;
  float acc[3][2][2][2] = {{{{0.f}}}};
  for (int phs = 0; phs < NPHS; ++phs) {
    for (int s = t; s < 1700; s += 256) {
      int c2 = s % 10, row = s / 10;
      int bh = row % 17, q = row / 17;
      int ad = q % 5, lic = q / 5;
      int id = id_base + ad, ih = ih_base + bh, iw = iwb + 2 * c2;
      float2 v = make_float2(0.f, 0.f);
      if ((id | ih | iw) >= 0)
        v = *(const float2*)&xn[(size_t)(phs * 2 + lic) * CHSTR + (id * HIN + ih) * WIN + iw];
      *(float2*)&xs[row * XSTR + 2 * c2] = v;
    }
    __syncthreads();
    if (t < 225) {
#pragma unroll
      for (int lic = 0; lic < 2; ++lic) {
        const float* wc = wsw + (size_t)(phs * 2 + lic) * 128;
        const float* xc = &xs[(lic * 85 + lmh) * XSTR + cb];
        float xv[5][3][3];
#pragma unroll
        for (int a = 0; a < 5; ++a)
#pragma unroll
          for (int b = 0; b < 3; ++b) {
            const float* xr = xc + (a * 17 + b) * XSTR;
            xv[a][b][0] = xr[0]; xv[a][b][1] = xr[1]; xv[a][b][2] = xr[2];
          }
#pragma unroll
        for (int kd = 0; kd < 5; ++kd) {
          constexpr int DT[5] = {0, 1, 0, 1, 0};
          constexpr int AOFF[5] = {2, 2, 1, 1, 0};
          const int dt = DT[kd], aoff = AOFF[kd];
          float wv[25];
#pragma unroll
          for (int j = 0; j < 25; ++j) wv[j] = wc[kd * 25 + j];
#pragma unroll
          for (int kh = 0; kh < 5; ++kh) {
            constexpr int HT[5] = {0, 1, 0, 1, 0};
            constexpr int BOFF[5] = {2, 2, 1, 1, 0};
            const int ht = HT[kh], boff = BOFF[kh];
#pragma unroll
            for (int m = 0; m < 3; ++m) {
              const float x0 = xv[m + aoff][boff][0];
              const float x1 = xv[m + aoff][boff][1];
              const float x2 = xv[m + aoff][boff][2];
              acc[m][dt][ht][0] += x0 * wv[kh * 5 + 4];
              acc[m][dt][ht][0] += x1 * wv[kh * 5 + 2];
              acc[m][dt][ht][0] += x2 * wv[kh * 5 + 0];
              acc[m][dt][ht][1] += x1 * wv[kh * 5 + 3];
              acc[m][dt][ht][1] += x2 * wv[kh * 5 + 1];
            }
          }
        }
      }
    }
    __syncthreads();
  }
  if (t < 225) {
    float* pb = part + (size_t)chunk * Y_TOT + (size_t)n * Y_N;
#pragma unroll
    for (int m = 0; m < 3; ++m)
#pragma unroll
      for (int dt = 0; dt < 2; ++dt)
#pragma unroll
        for (int ht = 0; ht < 2; ++ht) {
          int od_g = 6 * dc + 2 * m + dt;
          int oh_g = 30 * hq + 2 * lmh + ht;
          int ow_g = 30 * wq + 2 * mw;
          *(float2*)&pb[(od_g * 60 + oh_g) * 60 + ow_g] =
              make_float2(acc[m][dt][ht][0], acc[m][dt][ht][1]);
        }
  }
}

template<int NCHUNK>
__global__ __launch_bounds__(256) void pool_stage2(const float* __restrict__ part,
                                                   const float* __restrict__ ws,
                                                   float* __restrict__ out, int woff) {
  __shared__ __align__(16) float buf[2160];
  __shared__ float red[240];
  int blk = blockIdx.x;
  int hc = blk % 10, dc = (blk / 10) % 5, n = blk / 50;
  int t = threadIdx.x;
  const float* pb = part + (size_t)n * Y_N;
  for (int s = t; s < 540; s += 256) {
    int row = s / 15, c4 = s % 15;
    int od = row / 6, oh = row % 6;
    size_t idx = (size_t)((6 * dc + od) * 60 + (6 * hc + oh)) * 60 + 4 * c4;
    float4 v = *(const float4*)&pb[idx];
#pragma unroll
    for (int c = 1; c < NCHUNK; ++c) {
      float4 u = *(const float4*)&pb[(size_t)c * Y_TOT + idx];
      v.x += u.x; v.y += u.y; v.z += u.z; v.w += u.w;
    }
    *(float4*)&buf[row * 60 + 4 * c4] = v;
  }
  __syncthreads();
  if (t < 240) {
    int wc = t / 24, sub = t % 24;
    float m = -3.4e38f;
#pragma unroll
    for (int k = 0; k < 9; ++k) {
      int e = sub + 24 * k;
      int od = e / 36, r = e % 36;
      int oh = r / 6, ow0 = r % 6;
      m = fmaxf(m, buf[(od * 6 + oh) * 60 + 6 * wc + ow0]);
    }
    red[t] = m;
  }
  __syncthreads();
  if (t < 10) {
    float mm = -3.4e38f;
#pragma unroll
    for (int s2 = 0; s2 < 24; ++s2) mm = fmaxf(mm, red[t * 24 + s2]);
    out[((n * 5 + dc) * 10 + hc) * 10 + t] = mm + ws[woff + 4096];
  }
}

__global__ __launch_bounds__(128) void prep2(const float* __restrict__ w,
                                             const float* __restrict__ bias,
                                             float* __restrict__ ws, int woff) {
  int i = blockIdx.x, t = threadIdx.x;
  if (t < 125) {
    const float* wp = w + (size_t)i * 64 * 125 + t;
    float v = 0.f;
#pragma unroll
    for (int o = 0; o < 64; ++o) v += wp[o * 125];
    ws[woff + i * 128 + t] = v;
  }
  if (i == 0 && t == 126) {
    float b = 0.f;
    for (int o = 0; o < 64; ++o) b += bias[o];
    ws[woff + 4096] = b;
  }
}

// ---------------- launch ----------------------------------------------
extern "C" void kernel_launch(void* const* d_in, const int* in_sizes, int n_in,
                              void* d_out, int out_size, void* d_ws, size_t ws_size,
                              hipStream_t stream) {
  const float* x    = (const float*)d_in[0];
  const float* w    = (const float*)d_in[1];
  const float* bias = (const float*)d_in[2];
  float* outp = (float*)d_out;

  if (ws_size >= (size_t)NEED_MFMA) {
    ushort_t* xT = (ushort_t*)d_ws;
    ushort_t* Bt = (ushort_t*)((char*)d_ws + BT_BYTE_OFF);
    float* wsf   = (float*)((char*)d_ws + WSF_BYTE_OFF);
    transpose_x<<<1088 + 27, 256, 0, stream>>>(x, w, bias, xT, Bt, wsf);
    conv_mfma<<<800, 576, 0, stream>>>(xT, Bt, wsf, outp);
    return;
  }

  float* ws = (float*)d_ws;
  const size_t need4 = ((size_t)4 * Y_TOT + 4097) * 4;
  const size_t need2 = ((size_t)2 * Y_TOT + 4097) * 4;
  const size_t need1 = ((size_t)1 * Y_TOT + 4097) * 4;
  if (ws_size >= need4) {
    int woff = 4 * Y_TOT;
    prep2<<<32, 128, 0, stream>>>(w, bias, ws, woff);
    conv_stage1<4><<<320 * 4, 256, 0, stream>>>(x, ws, ws, woff);
    pool_stage2<4><<<800, 256, 0, stream>>>(ws, ws, outp, woff);
  } else if (ws_size >= need2) {
    int woff = 2 * Y_TOT;
    prep2<<<32, 128, 0, stream>>>(w, bias, ws, woff);
    conv_stage1<2><<<320 * 2, 256, 0, stream>>>(x, ws, ws, woff);
    pool_stage2<2><<<800, 256, 0, stream>>>(ws, ws, outp, woff);
  } else if (ws_size >= need1) {
    int woff = 1 * Y_TOT;
    prep2<<<32, 128, 0, stream>>>(w, bias, ws, woff);
    conv_stage1<1><<<320 * 1, 256, 0, stream>>>(x, ws, ws, woff);
    pool_stage2<1><<<800, 256, 0, stream>>>(ws, ws, outp, woff);
  }
}